// Round 6
// baseline (144.519 us; speedup 1.0000x reference)
//
#include <hip/hip_runtime.h>
#include <hip/hip_bf16.h>

// ---- types ----
typedef float  f32x4  __attribute__((ext_vector_type(4)));
typedef __bf16 bf16x8 __attribute__((ext_vector_type(8)));
typedef __bf16 bf16x4 __attribute__((ext_vector_type(4)));
typedef __bf16 bf16x2 __attribute__((ext_vector_type(2)));

#define T_SEQ   2048
#define HIDDEN  2048
#define NH      32
#define NKV     4
#define HD      64
#define QSZ     2048
#define KVSZ    256
#define QKVN    2560
#define WINDOW  1024
// SCALE * log2(e): scores computed in log2 domain
#define QSCALE  0.1803368801111f

__device__ __forceinline__ void gll16(const __bf16* g, __bf16* l) {
    __builtin_amdgcn_global_load_lds(
        (const __attribute__((address_space(1))) void*)g,
        (__attribute__((address_space(3))) void*)l,
        16, 0, 0);
}

// ---------------- convert f32 -> bf16 (vectorized) ----------------
__global__ __launch_bounds__(256) void cvt_f32_bf16(const float4* __restrict__ in,
                                                    bf16x4* __restrict__ out) {
    int id = blockIdx.x * 256 + threadIdx.x;
    float4 v = in[id];
    bf16x4 o;
    o[0] = (__bf16)v.x; o[1] = (__bf16)v.y; o[2] = (__bf16)v.z; o[3] = (__bf16)v.w;
    out[id] = o;
}

// ---------------- transpose f32 [Rin][Cin] -> bf16 [Cin][Rin] ----------------
__global__ __launch_bounds__(256) void transpose_f32_bf16(const float* __restrict__ in,
                                                          __bf16* __restrict__ out,
                                                          int Rin, int Cin) {
    __shared__ float tile[32][33];
    int r = threadIdx.x >> 5;
    int c = threadIdx.x & 31;
    int ri = blockIdx.y * 32, ci = blockIdx.x * 32;
    #pragma unroll
    for (int i = 0; i < 4; i++)
        tile[r + i*8][c] = in[(size_t)(ri + r + i*8) * Cin + ci + c];
    __syncthreads();
    #pragma unroll
    for (int i = 0; i < 4; i++)
        out[(size_t)(ci + r + i*8) * Rin + ri + c] = (__bf16)tile[c][r + i*8];
}

// ================= GEMM core (shared macros) =================
// single-buffered m97 structure: STAGE -> barrier -> 32 MFMA -> barrier.
// gll16 width-16 staging, linear LDS, XOR-swizzled source & read, XCD swizzle.

#define GEMM_PROLOGUE(Aptr, Btptr, Kdim)                                        \
    __shared__ __align__(16) __bf16 Asm[128 * 64];                              \
    __shared__ __align__(16) __bf16 Bsm[128 * 64];                              \
    const int tid = threadIdx.x;                                                \
    const int wid = tid >> 6;                                                   \
    const int l   = tid & 63;                                                   \
    const int lg  = l >> 4;                                                     \
    const int ll  = l & 15;                                                     \
    const int swl = ll & 7;                                                     \
    const int wm  = wid >> 1, wn = wid & 1;                                     \
    const int gx   = gridDim.x;                                                 \
    const int flat = blockIdx.y * gx + blockIdx.x;                              \
    const int nwg  = gx * gridDim.y;                                            \
    const int swz  = (flat & 7) * (nwg >> 3) + (flat >> 3);                     \
    const int bm   = (swz / gx) * 128;                                          \
    const int bn   = (swz % gx) * 128;                                          \
    const __bf16* Ab = (Aptr) + (size_t)bm * (Kdim);                            \
    const __bf16* Bb = (Btptr) + (size_t)bn * (Kdim);                           \
    f32x4 acc[4][4];                                                            \
    _Pragma("unroll")                                                           \
    for (int i = 0; i < 4; i++)                                                 \
        _Pragma("unroll")                                                       \
        for (int j = 0; j < 4; j++)                                             \
            acc[i][j] = (f32x4){0.f, 0.f, 0.f, 0.f};                            \
    const int srow = tid >> 3;                                                  \
    const int sseg0 = tid & 7;

#define GEMM_KLOOP(Kdim)                                                        \
    for (int k0 = 0; k0 < (Kdim); k0 += 64) {                                   \
        _Pragma("unroll")                                                       \
        for (int c = 0; c < 4; c++) {                                           \
            int row  = c * 32 + srow;                                           \
            int sseg = sseg0 ^ (row & 7);                                       \
            gll16(Ab + (size_t)row * (Kdim) + k0 + sseg * 8,                    \
                  &Asm[(c * 256 + wid * 64) * 8]);                              \
            gll16(Bb + (size_t)row * (Kdim) + k0 + sseg * 8,                    \
                  &Bsm[(c * 256 + wid * 64) * 8]);                              \
        }                                                                       \
        __syncthreads();                                                        \
        _Pragma("unroll")                                                       \
        for (int ss = 0; ss < 2; ss++) {                                        \
            bf16x8 af[4], bfr[4];                                               \
            _Pragma("unroll")                                                   \
            for (int mi = 0; mi < 4; mi++) {                                    \
                int r = wm * 64 + mi * 16 + ll;                                 \
                int u = (ss * 4 + lg) ^ swl;                                    \
                af[mi] = *reinterpret_cast<const bf16x8*>(&Asm[r * 64 + u * 8]);\
            }                                                                   \
            _Pragma("unroll")                                                   \
            for (int ni = 0; ni < 4; ni++) {                                    \
                int r = wn * 64 + ni * 16 + ll;                                 \
                int u = (ss * 4 + lg) ^ swl;                                    \
                bfr[ni] = *reinterpret_cast<const bf16x8*>(&Bsm[r * 64 + u * 8]);\
            }                                                                   \
            _Pragma("unroll")                                                   \
            for (int mi = 0; mi < 4; mi++)                                      \
                _Pragma("unroll")                                               \
                for (int ni = 0; ni < 4; ni++)                                  \
                    acc[mi][ni] = __builtin_amdgcn_mfma_f32_16x16x32_bf16(      \
                        af[mi], bfr[ni], acc[mi][ni], 0, 0, 0);                 \
        }                                                                       \
        __syncthreads();                                                        \
    }

// ---------------- GEMM2: C[M][N] = A * Bt^T, fp32 out ----------------
__global__ __launch_bounds__(256) void gemm_out(const __bf16* __restrict__ A,
                                                const __bf16* __restrict__ Bt,
                                                float* __restrict__ Cout,
                                                int M, int N, int K) {
    GEMM_PROLOGUE(A, Bt, K)
    GEMM_KLOOP(K)
    #pragma unroll
    for (int mi = 0; mi < 4; mi++)
        #pragma unroll
        for (int ni = 0; ni < 4; ni++)
            #pragma unroll
            for (int r = 0; r < 4; r++) {
                int row = bm + wm*64 + mi*16 + lg*4 + r;
                int col = bn + wn*64 + ni*16 + ll;
                Cout[(size_t)row * N + col] = acc[mi][ni][r];
            }
}

// ---------------- GEMM1 fused: qkv proj + RoPE + split + V-transpose ----------------
// N = QKVN (2560), K = HIDDEN. Tile roles by bn: q (<2048), k (<2304), v (else).
// RoPE pair (f, f+32) = (acc[mi][ni], acc[mi][ni^2]) — thread-local.
__global__ __launch_bounds__(256) void gemm_qkv(const __bf16* __restrict__ A,
                                                const __bf16* __restrict__ Bt,
                                                const int* __restrict__ pos,
                                                __bf16* __restrict__ q,
                                                __bf16* __restrict__ k,
                                                __bf16* __restrict__ vT) {
    GEMM_PROLOGUE(A, Bt, HIDDEN)
    GEMM_KLOOP(HIDDEN)

    if (bn < QSZ + KVSZ) {
        // q or k: apply NeoX RoPE; q additionally scaled by QSCALE
        const bool isq = (bn < QSZ);
        const float ifr0 = exp2f((float)ll * -0.62286151779138f);
        const float ifr1 = exp2f((float)(16 + ll) * -0.62286151779138f);
        #pragma unroll
        for (int mi = 0; mi < 4; mi++) {
            #pragma unroll
            for (int r = 0; r < 4; r++) {
                int row = bm + wm*64 + mi*16 + lg*4 + r;
                float p = (float)pos[row];
                #pragma unroll
                for (int ni = 0; ni < 2; ni++) {
                    float ang = p * (ni ? ifr1 : ifr0);
                    float sn, cs;
                    sincosf(ang, &sn, &cs);
                    float x1 = acc[mi][ni][r], x2 = acc[mi][ni + 2][r];
                    float o1 = x1 * cs - x2 * sn;
                    float o2 = x2 * cs + x1 * sn;
                    int col = bn + wn*64 + ni*16 + ll;
                    if (isq) {
                        q[(size_t)row * QSZ + col]      = (__bf16)(o1 * QSCALE);
                        q[(size_t)row * QSZ + col + 32] = (__bf16)(o2 * QSCALE);
                    } else {
                        k[(size_t)row * KVSZ + (col - QSZ)]      = (__bf16)o1;
                        k[(size_t)row * KVSZ + (col - QSZ) + 32] = (__bf16)o2;
                    }
                }
            }
        }
    } else {
        // v: no rope; transposed write vT[d][token], 4 tokens packed per store
        #pragma unroll
        for (int mi = 0; mi < 4; mi++) {
            int row0 = bm + wm*64 + mi*16 + lg*4;
            #pragma unroll
            for (int ni = 0; ni < 4; ni++) {
                int d = bn + wn*64 + ni*16 + ll - (QSZ + KVSZ);
                bf16x4 pk;
                #pragma unroll
                for (int r = 0; r < 4; r++) pk[r] = (__bf16)acc[mi][ni][r];
                *reinterpret_cast<bf16x4*>(&vT[(size_t)d * T_SEQ + row0]) = pk;
            }
        }
    }
}

// ---------------- sliding-window GQA flash attention ----------------
// 512 threads = 8 waves; 2 query-heads (same kv-head) per block, 64 q-rows.
// Swapped QK^T (lane owns q-row), no running max, gll16 double-buffered K/V^T.
__global__ __launch_bounds__(512) void attn_kernel(const __bf16* __restrict__ qg,
                                                   const __bf16* __restrict__ kgl,
                                                   const __bf16* __restrict__ vTg,
                                                   __bf16* __restrict__ og) {
    const int qb  = blockIdx.x;
    const int hp  = blockIdx.y;          // head pair 0..15
    const int kvh = hp >> 2;
    const int tid = threadIdx.x;
    const int wid = tid >> 6;            // 0..7
    const int h   = hp * 2 + (wid >> 2);
    const int l   = tid & 63;
    const int lg  = l >> 4;
    const int ll  = l & 15;
    const int i0  = qb * 64;
    const int qw  = i0 + (wid & 3) * 16;
    const int qi  = qw + ll;

    __shared__ __align__(16) __bf16 Ksm[2][64 * 64];
    __shared__ __align__(16) __bf16 VTs[2][64 * 64];
    __shared__ __align__(16) __bf16 Psm[8][16][72];

    bf16x8 qf[2];
    {
        const __bf16* qp = qg + (size_t)(qw + ll) * QSZ + h * 64 + lg * 8;
        qf[0] = *reinterpret_cast<const bf16x8*>(qp);
        qf[1] = *reinterpret_cast<const bf16x8*>(qp + 32);
    }

    f32x4 o[4];
    #pragma unroll
    for (int dn = 0; dn < 4; dn++) o[dn] = (f32x4){0.f, 0.f, 0.f, 0.f};
    float l_run = 0.f;

    int jlo = i0 - (WINDOW - 1); if (jlo < 0) jlo = 0;
    int t0v = jlo & ~63;
    int tend = i0 + 64;

    const int srow = tid >> 3;                       // 0..63
    const int sg   = (tid & 7) ^ (srow & 7);
    const __bf16* kp = kgl + (size_t)srow * KVSZ + kvh * 64 + sg * 8;
    const __bf16* vp = vTg + (size_t)(kvh * 64 + srow) * T_SEQ + sg * 8;

#define ASTAGE(buf, t)                                   \
    {                                                    \
        gll16(kp + (size_t)(t) * KVSZ, &Ksm[buf][tid * 8]); \
        gll16(vp + (t),                &VTs[buf][tid * 8]); \
    }

    ASTAGE(0, t0v);
    __syncthreads();

    const int swl = ll & 7;
    const int u0 = (lg ^ swl) * 8;
    const int u1 = ((4 + lg) ^ swl) * 8;

    int cur = 0;
    for (int t = t0v; t < tend; t += 64) {
        if (t + 64 < tend) ASTAGE(cur ^ 1, t + 64);

        bool active = (t <= qw + 15) && (t + 63 >= qw - (WINDOW - 1));
        if (active) {
            f32x4 sT[4];
            __builtin_amdgcn_s_setprio(1);
            #pragma unroll
            for (int kt = 0; kt < 4; kt++) {
                sT[kt] = (f32x4){0.f, 0.f, 0.f, 0.f};
                bf16x8 kf0 = *reinterpret_cast<const bf16x8*>(&Ksm[cur][kt*1024 + ll*64 + u0]);
                sT[kt] = __builtin_amdgcn_mfma_f32_16x16x32_bf16(kf0, qf[0], sT[kt], 0, 0, 0);
                bf16x8 kf1 = *reinterpret_cast<const bf16x8*>(&Ksm[cur][kt*1024 + ll*64 + u1]);
                sT[kt] = __builtin_amdgcn_mfma_f32_16x16x32_bf16(kf1, qf[1], sT[kt], 0, 0, 0);
            }
            __builtin_amdgcn_s_setprio(0);

            bool full = (t + 63 <= qw) && (t >= qw + 15 - (WINDOW - 1));
            float ts = 0.f;
            #pragma unroll
            for (int kt = 0; kt < 4; kt++) {
                float p0, p1, p2, p3;
                if (full) {
                    p0 = exp2f(sT[kt][0]);
                    p1 = exp2f(sT[kt][1]);
                    p2 = exp2f(sT[kt][2]);
                    p3 = exp2f(sT[kt][3]);
                } else {
                    int j = t + kt * 16 + lg * 4;
                    bool ok0 = (j     <= qi) && (qi - j     < WINDOW);
                    bool ok1 = (j + 1 <= qi) && (qi - j - 1 < WINDOW);
                    bool ok2 = (j + 2 <= qi) && (qi - j - 2 < WINDOW);
                    bool ok3 = (j + 3 <= qi) && (qi - j - 3 < WINDOW);
                    p0 = ok0 ? exp2f(sT[kt][0]) : 0.f;
                    p1 = ok1 ? exp2f(sT[kt][1]) : 0.f;
                    p2 = ok2 ? exp2f(sT[kt][2]) : 0.f;
                    p3 = ok3 ? exp2f(sT[kt][3]) : 0.f;
                }
                ts += (p0 + p1) + (p2 + p3);
                *reinterpret_cast<bf16x2*>(&Psm[wid][ll][kt*16 + lg*4])     = (bf16x2){(__bf16)p0, (__bf16)p1};
                *reinterpret_cast<bf16x2*>(&Psm[wid][ll][kt*16 + lg*4 + 2]) = (bf16x2){(__bf16)p2, (__bf16)p3};
            }
            ts += __shfl_xor(ts, 16);
            ts += __shfl_xor(ts, 32);
            l_run += ts;

            __builtin_amdgcn_s_setprio(1);
            #pragma unroll
            for (int kt2 = 0; kt2 < 2; kt2++) {
                bf16x8 pa = *reinterpret_cast<const bf16x8*>(&Psm[wid][ll][kt2*32 + lg*8]);
                int uv = kt2 ? u1 : u0;
                #pragma unroll
                for (int dn = 0; dn < 4; dn++) {
                    bf16x8 vf = *reinterpret_cast<const bf16x8*>(&VTs[cur][dn*1024 + ll*64 + uv]);
                    o[dn] = __builtin_amdgcn_mfma_f32_16x16x32_bf16(pa, vf, o[dn], 0, 0, 0);
                }
            }
            __builtin_amdgcn_s_setprio(0);
        }
        __syncthreads();
        cur ^= 1;
    }
#undef ASTAGE

    float linv = 1.0f / l_run;
    float i0v = __shfl(linv, lg*4 + 0);
    float i1v = __shfl(linv, lg*4 + 1);
    float i2v = __shfl(linv, lg*4 + 2);
    float i3v = __shfl(linv, lg*4 + 3);
    #pragma unroll
    for (int dn = 0; dn < 4; dn++) {
        og[(size_t)(qw + lg*4 + 0) * QSZ + h*64 + dn*16 + ll] = (__bf16)(o[dn][0] * i0v);
        og[(size_t)(qw + lg*4 + 1) * QSZ + h*64 + dn*16 + ll] = (__bf16)(o[dn][1] * i1v);
        og[(size_t)(qw + lg*4 + 2) * QSZ + h*64 + dn*16 + ll] = (__bf16)(o[dn][2] * i2v);
        og[(size_t)(qw + lg*4 + 3) * QSZ + h*64 + dn*16 + ll] = (__bf16)(o[dn][3] * i3v);
    }
}

// ---------------- launch ----------------
extern "C" void kernel_launch(void* const* d_in, const int* in_sizes, int n_in,
                              void* d_out, int out_size, void* d_ws, size_t ws_size,
                              hipStream_t stream) {
    const int*   positions = (const int*)d_in[0];
    const float* hidden    = (const float*)d_in[1];
    const float* wqkv      = (const float*)d_in[2];
    const float* wo        = (const float*)d_in[3];
    float* out = (float*)d_out;

    char* ws = (char*)d_ws;
    __bf16* hidden_bf = (__bf16*)(ws);                       // 2048x2048
    __bf16* wqkv_t    = (__bf16*)(ws + 8388608);             // 2560x2048
    __bf16* wo_t      = (__bf16*)(ws + 18874368);            // 2048x2048
    __bf16* q_bf      = (__bf16*)(ws + 37748736);            // 2048x2048
    __bf16* k_bf      = (__bf16*)(ws + 46137344);            // 2048x256
    __bf16* vT_bf     = (__bf16*)(ws + 47185920);            // 256x2048 (V^T)
    __bf16* attn_bf   = (__bf16*)(ws + 48234496);            // 2048x2048

    cvt_f32_bf16<<<dim3((T_SEQ * HIDDEN) / 4 / 256), dim3(256), 0, stream>>>(
        (const float4*)hidden, (bf16x4*)hidden_bf);
    transpose_f32_bf16<<<dim3(QKVN / 32, HIDDEN / 32), dim3(256), 0, stream>>>(
        wqkv, wqkv_t, HIDDEN, QKVN);
    transpose_f32_bf16<<<dim3(HIDDEN / 32, QSZ / 32), dim3(256), 0, stream>>>(
        wo, wo_t, QSZ, HIDDEN);

    // fused qkv-proj + rope + split + v-transpose
    gemm_qkv<<<dim3(QKVN / 128, T_SEQ / 128), dim3(256), 0, stream>>>(
        hidden_bf, wqkv_t, positions, q_bf, k_bf, vT_bf);

    attn_kernel<<<dim3(T_SEQ / 64, 16), dim3(512), 0, stream>>>(
        q_bf, k_bf, vT_bf, attn_bf);

    gemm_out<<<dim3(HIDDEN / 128, T_SEQ / 128), dim3(256), 0, stream>>>(
        attn_bf, wo_t, out, T_SEQ, HIDDEN, QSZ);
}

// Round 7
// 122.592 us; speedup vs baseline: 1.1789x; 1.1789x over previous
//
#include <hip/hip_runtime.h>
#include <hip/hip_bf16.h>

// ---- types ----
typedef float  f32x4  __attribute__((ext_vector_type(4)));
typedef __bf16 bf16x8 __attribute__((ext_vector_type(8)));
typedef __bf16 bf16x4 __attribute__((ext_vector_type(4)));
typedef __bf16 bf16x2 __attribute__((ext_vector_type(2)));

#define T_SEQ   2048
#define HIDDEN  2048
#define NH      32
#define NKV     4
#define HD      64
#define QSZ     2048
#define KVSZ    256
#define QKVN    2560
#define WINDOW  1024
// SCALE * log2(e): scores computed in log2 domain
#define QSCALE  0.1803368801111f

__device__ __forceinline__ void gll16(const __bf16* g, __bf16* l) {
    __builtin_amdgcn_global_load_lds(
        (const __attribute__((address_space(1))) void*)g,
        (__attribute__((address_space(3))) void*)l,
        16, 0, 0);
}

// ---------------- convert f32 -> bf16 (vectorized) ----------------
__global__ __launch_bounds__(256) void cvt_f32_bf16(const float4* __restrict__ in,
                                                    bf16x4* __restrict__ out) {
    int id = blockIdx.x * 256 + threadIdx.x;
    float4 v = in[id];
    bf16x4 o;
    o[0] = (__bf16)v.x; o[1] = (__bf16)v.y; o[2] = (__bf16)v.z; o[3] = (__bf16)v.w;
    out[id] = o;
}

// ---------------- transpose f32 [Rin][Cin] -> bf16 [Cin][Rin] ----------------
__global__ __launch_bounds__(256) void transpose_f32_bf16(const float* __restrict__ in,
                                                          __bf16* __restrict__ out,
                                                          int Rin, int Cin) {
    __shared__ float tile[32][33];
    int r = threadIdx.x >> 5;
    int c = threadIdx.x & 31;
    int ri = blockIdx.y * 32, ci = blockIdx.x * 32;
    #pragma unroll
    for (int i = 0; i < 4; i++)
        tile[r + i*8][c] = in[(size_t)(ri + r + i*8) * Cin + ci + c];
    __syncthreads();
    #pragma unroll
    for (int i = 0; i < 4; i++)
        out[(size_t)(ci + r + i*8) * Rin + ri + c] = (__bf16)tile[c][r + i*8];
}

// ================= GEMM core (shared macros) =================
// Tile 64(M) x 128(N), 256 threads = 4 waves, wave tile 32x64.
// 2-phase double-buffered K-loop: STAGE(next) issued before compute(cur).
// gll16 width-16 staging, linear LDS, XOR-swizzled source & read, XCD swizzle.

#define GEMM_PROLOGUE(Aptr, Btptr, Kdim)                                        \
    __shared__ __align__(16) __bf16 Asm[2][64 * 64];                            \
    __shared__ __align__(16) __bf16 Bsm[2][128 * 64];                           \
    const int tid = threadIdx.x;                                                \
    const int wid = tid >> 6;                                                   \
    const int l   = tid & 63;                                                   \
    const int lg  = l >> 4;                                                     \
    const int ll  = l & 15;                                                     \
    const int swl = ll & 7;                                                     \
    const int wm  = wid >> 1, wn = wid & 1;                                     \
    const int gx   = gridDim.x;                                                 \
    const int flat = blockIdx.y * gx + blockIdx.x;                              \
    const int nwg  = gx * gridDim.y;                                            \
    const int swz  = (flat & 7) * (nwg >> 3) + (flat >> 3);                     \
    const int bm   = (swz / gx) * 64;                                           \
    const int bn   = (swz % gx) * 128;                                          \
    const __bf16* Ab = (Aptr) + (size_t)bm * (Kdim);                            \
    const __bf16* Bb = (Btptr) + (size_t)bn * (Kdim);                           \
    f32x4 acc[2][4];                                                            \
    _Pragma("unroll")                                                           \
    for (int i = 0; i < 2; i++)                                                 \
        _Pragma("unroll")                                                       \
        for (int j = 0; j < 4; j++)                                             \
            acc[i][j] = (f32x4){0.f, 0.f, 0.f, 0.f};                            \
    const int srow = tid >> 3;                                                  \
    const int sseg0 = tid & 7;

#define GEMM_STAGE(buf, k0, Kdim)                                               \
    {                                                                           \
        _Pragma("unroll")                                                       \
        for (int c = 0; c < 2; c++) {                                           \
            int row  = c * 32 + srow;                                           \
            int sseg = sseg0 ^ (row & 7);                                       \
            gll16(Ab + (size_t)row * (Kdim) + (k0) + sseg * 8,                  \
                  &Asm[buf][(c * 256 + tid) * 8]);                              \
        }                                                                       \
        _Pragma("unroll")                                                       \
        for (int c = 0; c < 4; c++) {                                           \
            int row  = c * 32 + srow;                                           \
            int sseg = sseg0 ^ (row & 7);                                       \
            gll16(Bb + (size_t)row * (Kdim) + (k0) + sseg * 8,                  \
                  &Bsm[buf][(c * 256 + tid) * 8]);                              \
        }                                                                       \
    }

#define GEMM_KLOOP(Kdim)                                                        \
    GEMM_STAGE(0, 0, Kdim)                                                      \
    __syncthreads();                                                            \
    int cur = 0;                                                                \
    for (int k0 = 0; k0 < (Kdim); k0 += 64) {                                   \
        if (k0 + 64 < (Kdim)) GEMM_STAGE(cur ^ 1, k0 + 64, Kdim)                \
        _Pragma("unroll")                                                       \
        for (int ss = 0; ss < 2; ss++) {                                        \
            bf16x8 af[2], bfr[4];                                               \
            _Pragma("unroll")                                                   \
            for (int mi = 0; mi < 2; mi++) {                                    \
                int r = wm * 32 + mi * 16 + ll;                                 \
                int u = (ss * 4 + lg) ^ swl;                                    \
                af[mi] = *reinterpret_cast<const bf16x8*>(&Asm[cur][r * 64 + u * 8]); \
            }                                                                   \
            _Pragma("unroll")                                                   \
            for (int ni = 0; ni < 4; ni++) {                                    \
                int r = wn * 64 + ni * 16 + ll;                                 \
                int u = (ss * 4 + lg) ^ swl;                                    \
                bfr[ni] = *reinterpret_cast<const bf16x8*>(&Bsm[cur][r * 64 + u * 8]); \
            }                                                                   \
            _Pragma("unroll")                                                   \
            for (int mi = 0; mi < 2; mi++)                                      \
                _Pragma("unroll")                                               \
                for (int ni = 0; ni < 4; ni++)                                  \
                    acc[mi][ni] = __builtin_amdgcn_mfma_f32_16x16x32_bf16(      \
                        af[mi], bfr[ni], acc[mi][ni], 0, 0, 0);                 \
        }                                                                       \
        __syncthreads();                                                        \
        cur ^= 1;                                                               \
    }

// ---------------- GEMM2: C[M][N] = A * Bt^T, fp32 out ----------------
__global__ __launch_bounds__(256) void gemm_out(const __bf16* __restrict__ A,
                                                const __bf16* __restrict__ Bt,
                                                float* __restrict__ Cout,
                                                int M, int N, int K) {
    GEMM_PROLOGUE(A, Bt, K)
    GEMM_KLOOP(K)
    #pragma unroll
    for (int mi = 0; mi < 2; mi++)
        #pragma unroll
        for (int ni = 0; ni < 4; ni++)
            #pragma unroll
            for (int r = 0; r < 4; r++) {
                int row = bm + wm*32 + mi*16 + lg*4 + r;
                int col = bn + wn*64 + ni*16 + ll;
                Cout[(size_t)row * N + col] = acc[mi][ni][r];
            }
}

// ---------------- GEMM1 fused: qkv proj + RoPE + split + V-transpose ----------------
// N = QKVN (2560), K = HIDDEN. Tile roles by bn: q (<2048), k (<2304), v (else).
// RoPE pair (f, f+32) = (acc[mi][ni], acc[mi][ni^2]) — thread-local.
__global__ __launch_bounds__(256) void gemm_qkv(const __bf16* __restrict__ A,
                                                const __bf16* __restrict__ Bt,
                                                const int* __restrict__ pos,
                                                __bf16* __restrict__ q,
                                                __bf16* __restrict__ k,
                                                __bf16* __restrict__ vT) {
    GEMM_PROLOGUE(A, Bt, HIDDEN)
    GEMM_KLOOP(HIDDEN)

    if (bn < QSZ + KVSZ) {
        // q or k: apply NeoX RoPE; q additionally scaled by QSCALE
        const bool isq = (bn < QSZ);
        const float ifr0 = exp2f((float)ll * -0.62286151779138f);
        const float ifr1 = exp2f((float)(16 + ll) * -0.62286151779138f);
        #pragma unroll
        for (int mi = 0; mi < 2; mi++) {
            #pragma unroll
            for (int r = 0; r < 4; r++) {
                int row = bm + wm*32 + mi*16 + lg*4 + r;
                float p = (float)pos[row];
                #pragma unroll
                for (int ni = 0; ni < 2; ni++) {
                    float ang = p * (ni ? ifr1 : ifr0);
                    float sn, cs;
                    sincosf(ang, &sn, &cs);
                    float x1 = acc[mi][ni][r], x2 = acc[mi][ni + 2][r];
                    float o1 = x1 * cs - x2 * sn;
                    float o2 = x2 * cs + x1 * sn;
                    int col = bn + wn*64 + ni*16 + ll;
                    if (isq) {
                        q[(size_t)row * QSZ + col]      = (__bf16)(o1 * QSCALE);
                        q[(size_t)row * QSZ + col + 32] = (__bf16)(o2 * QSCALE);
                    } else {
                        k[(size_t)row * KVSZ + (col - QSZ)]      = (__bf16)o1;
                        k[(size_t)row * KVSZ + (col - QSZ) + 32] = (__bf16)o2;
                    }
                }
            }
        }
    } else {
        // v: no rope; transposed write vT[d][token], 4 tokens packed per store
        #pragma unroll
        for (int mi = 0; mi < 2; mi++) {
            int row0 = bm + wm*32 + mi*16 + lg*4;
            #pragma unroll
            for (int ni = 0; ni < 4; ni++) {
                int d = bn + wn*64 + ni*16 + ll - (QSZ + KVSZ);
                bf16x4 pk;
                #pragma unroll
                for (int r = 0; r < 4; r++) pk[r] = (__bf16)acc[mi][ni][r];
                *reinterpret_cast<bf16x4*>(&vT[(size_t)d * T_SEQ + row0]) = pk;
            }
        }
    }
}

// ---------------- sliding-window GQA flash attention ----------------
// 512 threads = 8 waves; 2 query-heads (same kv-head) per block, 64 q-rows.
// Swapped QK^T (lane owns q-row), no running max, gll16 double-buffered K/V^T.
__global__ __launch_bounds__(512) void attn_kernel(const __bf16* __restrict__ qg,
                                                   const __bf16* __restrict__ kgl,
                                                   const __bf16* __restrict__ vTg,
                                                   __bf16* __restrict__ og) {
    const int qb  = blockIdx.x;
    const int hp  = blockIdx.y;          // head pair 0..15
    const int kvh = hp >> 2;
    const int tid = threadIdx.x;
    const int wid = tid >> 6;            // 0..7
    const int h   = hp * 2 + (wid >> 2);
    const int l   = tid & 63;
    const int lg  = l >> 4;
    const int ll  = l & 15;
    const int i0  = qb * 64;
    const int qw  = i0 + (wid & 3) * 16;
    const int qi  = qw + ll;

    __shared__ __align__(16) __bf16 Ksm[2][64 * 64];
    __shared__ __align__(16) __bf16 VTs[2][64 * 64];
    __shared__ __align__(16) __bf16 Psm[8][16][72];

    bf16x8 qf[2];
    {
        const __bf16* qp = qg + (size_t)(qw + ll) * QSZ + h * 64 + lg * 8;
        qf[0] = *reinterpret_cast<const bf16x8*>(qp);
        qf[1] = *reinterpret_cast<const bf16x8*>(qp + 32);
    }

    f32x4 o[4];
    #pragma unroll
    for (int dn = 0; dn < 4; dn++) o[dn] = (f32x4){0.f, 0.f, 0.f, 0.f};
    float l_run = 0.f;

    int jlo = i0 - (WINDOW - 1); if (jlo < 0) jlo = 0;
    int t0v = jlo & ~63;
    int tend = i0 + 64;

    const int srow = tid >> 3;                       // 0..63
    const int sg   = (tid & 7) ^ (srow & 7);
    const __bf16* kp = kgl + (size_t)srow * KVSZ + kvh * 64 + sg * 8;
    const __bf16* vp = vTg + (size_t)(kvh * 64 + srow) * T_SEQ + sg * 8;

#define ASTAGE(buf, t)                                   \
    {                                                    \
        gll16(kp + (size_t)(t) * KVSZ, &Ksm[buf][tid * 8]); \
        gll16(vp + (t),                &VTs[buf][tid * 8]); \
    }

    ASTAGE(0, t0v);
    __syncthreads();

    const int swl = ll & 7;
    const int u0 = (lg ^ swl) * 8;
    const int u1 = ((4 + lg) ^ swl) * 8;

    int cur = 0;
    for (int t = t0v; t < tend; t += 64) {
        if (t + 64 < tend) ASTAGE(cur ^ 1, t + 64);

        bool active = (t <= qw + 15) && (t + 63 >= qw - (WINDOW - 1));
        if (active) {
            f32x4 sT[4];
            __builtin_amdgcn_s_setprio(1);
            #pragma unroll
            for (int kt = 0; kt < 4; kt++) {
                sT[kt] = (f32x4){0.f, 0.f, 0.f, 0.f};
                bf16x8 kf0 = *reinterpret_cast<const bf16x8*>(&Ksm[cur][kt*1024 + ll*64 + u0]);
                sT[kt] = __builtin_amdgcn_mfma_f32_16x16x32_bf16(kf0, qf[0], sT[kt], 0, 0, 0);
                bf16x8 kf1 = *reinterpret_cast<const bf16x8*>(&Ksm[cur][kt*1024 + ll*64 + u1]);
                sT[kt] = __builtin_amdgcn_mfma_f32_16x16x32_bf16(kf1, qf[1], sT[kt], 0, 0, 0);
            }
            __builtin_amdgcn_s_setprio(0);

            bool full = (t + 63 <= qw) && (t >= qw + 15 - (WINDOW - 1));
            float ts = 0.f;
            #pragma unroll
            for (int kt = 0; kt < 4; kt++) {
                float p0, p1, p2, p3;
                if (full) {
                    p0 = exp2f(sT[kt][0]);
                    p1 = exp2f(sT[kt][1]);
                    p2 = exp2f(sT[kt][2]);
                    p3 = exp2f(sT[kt][3]);
                } else {
                    int j = t + kt * 16 + lg * 4;
                    bool ok0 = (j     <= qi) && (qi - j     < WINDOW);
                    bool ok1 = (j + 1 <= qi) && (qi - j - 1 < WINDOW);
                    bool ok2 = (j + 2 <= qi) && (qi - j - 2 < WINDOW);
                    bool ok3 = (j + 3 <= qi) && (qi - j - 3 < WINDOW);
                    p0 = ok0 ? exp2f(sT[kt][0]) : 0.f;
                    p1 = ok1 ? exp2f(sT[kt][1]) : 0.f;
                    p2 = ok2 ? exp2f(sT[kt][2]) : 0.f;
                    p3 = ok3 ? exp2f(sT[kt][3]) : 0.f;
                }
                ts += (p0 + p1) + (p2 + p3);
                *reinterpret_cast<bf16x2*>(&Psm[wid][ll][kt*16 + lg*4])     = (bf16x2){(__bf16)p0, (__bf16)p1};
                *reinterpret_cast<bf16x2*>(&Psm[wid][ll][kt*16 + lg*4 + 2]) = (bf16x2){(__bf16)p2, (__bf16)p3};
            }
            ts += __shfl_xor(ts, 16);
            ts += __shfl_xor(ts, 32);
            l_run += ts;

            __builtin_amdgcn_s_setprio(1);
            #pragma unroll
            for (int kt2 = 0; kt2 < 2; kt2++) {
                bf16x8 pa = *reinterpret_cast<const bf16x8*>(&Psm[wid][ll][kt2*32 + lg*8]);
                int uv = kt2 ? u1 : u0;
                #pragma unroll
                for (int dn = 0; dn < 4; dn++) {
                    bf16x8 vf = *reinterpret_cast<const bf16x8*>(&VTs[cur][dn*1024 + ll*64 + uv]);
                    o[dn] = __builtin_amdgcn_mfma_f32_16x16x32_bf16(pa, vf, o[dn], 0, 0, 0);
                }
            }
            __builtin_amdgcn_s_setprio(0);
        }
        __syncthreads();
        cur ^= 1;
    }
#undef ASTAGE

    float linv = 1.0f / l_run;
    float i0v = __shfl(linv, lg*4 + 0);
    float i1v = __shfl(linv, lg*4 + 1);
    float i2v = __shfl(linv, lg*4 + 2);
    float i3v = __shfl(linv, lg*4 + 3);
    #pragma unroll
    for (int dn = 0; dn < 4; dn++) {
        og[(size_t)(qw + lg*4 + 0) * QSZ + h*64 + dn*16 + ll] = (__bf16)(o[dn][0] * i0v);
        og[(size_t)(qw + lg*4 + 1) * QSZ + h*64 + dn*16 + ll] = (__bf16)(o[dn][1] * i1v);
        og[(size_t)(qw + lg*4 + 2) * QSZ + h*64 + dn*16 + ll] = (__bf16)(o[dn][2] * i2v);
        og[(size_t)(qw + lg*4 + 3) * QSZ + h*64 + dn*16 + ll] = (__bf16)(o[dn][3] * i3v);
    }
}

// ---------------- launch ----------------
extern "C" void kernel_launch(void* const* d_in, const int* in_sizes, int n_in,
                              void* d_out, int out_size, void* d_ws, size_t ws_size,
                              hipStream_t stream) {
    const int*   positions = (const int*)d_in[0];
    const float* hidden    = (const float*)d_in[1];
    const float* wqkv      = (const float*)d_in[2];
    const float* wo        = (const float*)d_in[3];
    float* out = (float*)d_out;

    char* ws = (char*)d_ws;
    __bf16* hidden_bf = (__bf16*)(ws);                       // 2048x2048
    __bf16* wqkv_t    = (__bf16*)(ws + 8388608);             // 2560x2048
    __bf16* wo_t      = (__bf16*)(ws + 18874368);            // 2048x2048
    __bf16* q_bf      = (__bf16*)(ws + 37748736);            // 2048x2048
    __bf16* k_bf      = (__bf16*)(ws + 46137344);             // 2048x256
    __bf16* vT_bf     = (__bf16*)(ws + 47185920);            // 256x2048 (V^T)
    __bf16* attn_bf   = (__bf16*)(ws + 48234496);            // 2048x2048

    cvt_f32_bf16<<<dim3((T_SEQ * HIDDEN) / 4 / 256), dim3(256), 0, stream>>>(
        (const float4*)hidden, (bf16x4*)hidden_bf);
    transpose_f32_bf16<<<dim3(QKVN / 32, HIDDEN / 32), dim3(256), 0, stream>>>(
        wqkv, wqkv_t, HIDDEN, QKVN);
    transpose_f32_bf16<<<dim3(HIDDEN / 32, QSZ / 32), dim3(256), 0, stream>>>(
        wo, wo_t, QSZ, HIDDEN);

    // fused qkv-proj + rope + split + v-transpose (tile 64x128, grid 640)
    gemm_qkv<<<dim3(QKVN / 128, T_SEQ / 64), dim3(256), 0, stream>>>(
        hidden_bf, wqkv_t, positions, q_bf, k_bf, vT_bf);

    attn_kernel<<<dim3(T_SEQ / 64, 16), dim3(512), 0, stream>>>(
        q_bf, k_bf, vT_bf, attn_bf);

    // out proj (tile 64x128, grid 512)
    gemm_out<<<dim3(HIDDEN / 128, T_SEQ / 64), dim3(256), 0, stream>>>(
        attn_bf, wo_t, out, T_SEQ, HIDDEN, QSZ);
}

// Round 8
// 113.399 us; speedup vs baseline: 1.2744x; 1.0811x over previous
//
#include <hip/hip_runtime.h>
#include <hip/hip_bf16.h>

// ---- types ----
typedef float  f32x4  __attribute__((ext_vector_type(4)));
typedef __bf16 bf16x8 __attribute__((ext_vector_type(8)));
typedef __bf16 bf16x4 __attribute__((ext_vector_type(4)));
typedef __bf16 bf16x2 __attribute__((ext_vector_type(2)));

#define T_SEQ   2048
#define HIDDEN  2048
#define NH      32
#define NKV     4
#define HD      64
#define QSZ     2048
#define KVSZ    256
#define QKVN    2560
#define WINDOW  1024

// raw v_exp_f32 if available (log2-domain scores); else __expf (natural domain)
#if __has_builtin(__builtin_amdgcn_exp2f)
#define EXPS(x) __builtin_amdgcn_exp2f(x)
#define QSCALE  0.1803368801111f   /* 0.125 * log2(e) */
#else
#define EXPS(x) __expf(x)
#define QSCALE  0.125f
#endif

__device__ __forceinline__ void gll16(const __bf16* g, __bf16* l) {
    __builtin_amdgcn_global_load_lds(
        (const __attribute__((address_space(1))) void*)g,
        (__attribute__((address_space(3))) void*)l,
        16, 0, 0);
}

// ---------------- convert f32 -> bf16 (vectorized) ----------------
__global__ __launch_bounds__(256) void cvt_f32_bf16(const float4* __restrict__ in,
                                                    bf16x4* __restrict__ out) {
    int id = blockIdx.x * 256 + threadIdx.x;
    float4 v = in[id];
    bf16x4 o;
    o[0] = (__bf16)v.x; o[1] = (__bf16)v.y; o[2] = (__bf16)v.z; o[3] = (__bf16)v.w;
    out[id] = o;
}

// ---------------- transpose f32 [Rin][Cin] -> bf16 [Cin][Rin] ----------------
__global__ __launch_bounds__(256) void transpose_f32_bf16(const float* __restrict__ in,
                                                          __bf16* __restrict__ out,
                                                          int Rin, int Cin) {
    __shared__ float tile[32][33];
    int r = threadIdx.x >> 5;
    int c = threadIdx.x & 31;
    int ri = blockIdx.y * 32, ci = blockIdx.x * 32;
    #pragma unroll
    for (int i = 0; i < 4; i++)
        tile[r + i*8][c] = in[(size_t)(ri + r + i*8) * Cin + ci + c];
    __syncthreads();
    #pragma unroll
    for (int i = 0; i < 4; i++)
        out[(size_t)(ci + r + i*8) * Rin + ri + c] = (__bf16)tile[c][r + i*8];
}

// ================= GEMM core (shared macros) =================
// Tile 64(M) x 128(N), 256 threads = 4 waves, wave tile 32x64.
// 2-phase double-buffered K-loop; gll16 staging; XOR-swizzled source & read.

#define GEMM_PROLOGUE(Aptr, Btptr, Kdim)                                        \
    __shared__ __align__(16) __bf16 Asm[2][64 * 64];                            \
    __shared__ __align__(16) __bf16 Bsm[2][128 * 64];                           \
    const int tid = threadIdx.x;                                                \
    const int wid = tid >> 6;                                                   \
    const int l   = tid & 63;                                                   \
    const int lg  = l >> 4;                                                     \
    const int ll  = l & 15;                                                     \
    const int swl = ll & 7;                                                     \
    const int wm  = wid >> 1, wn = wid & 1;                                     \
    const int gx   = gridDim.x;                                                 \
    const int flat = blockIdx.y * gx + blockIdx.x;                              \
    const int nwg  = gx * gridDim.y;                                            \
    const int swz  = (flat & 7) * (nwg >> 3) + (flat >> 3);                     \
    const int bm   = (swz / gx) * 64;                                           \
    const int bn   = (swz % gx) * 128;                                          \
    const __bf16* Ab = (Aptr) + (size_t)bm * (Kdim);                            \
    const __bf16* Bb = (Btptr) + (size_t)bn * (Kdim);                           \
    f32x4 acc[2][4];                                                            \
    _Pragma("unroll")                                                           \
    for (int i = 0; i < 2; i++)                                                 \
        _Pragma("unroll")                                                       \
        for (int j = 0; j < 4; j++)                                             \
            acc[i][j] = (f32x4){0.f, 0.f, 0.f, 0.f};                            \
    const int srow = tid >> 3;                                                  \
    const int sseg0 = tid & 7;

#define GEMM_STAGE(buf, k0, Kdim)                                               \
    {                                                                           \
        _Pragma("unroll")                                                       \
        for (int c = 0; c < 2; c++) {                                           \
            int row  = c * 32 + srow;                                           \
            int sseg = sseg0 ^ (row & 7);                                       \
            gll16(Ab + (size_t)row * (Kdim) + (k0) + sseg * 8,                  \
                  &Asm[buf][(c * 256 + tid) * 8]);                              \
        }                                                                       \
        _Pragma("unroll")                                                       \
        for (int c = 0; c < 4; c++) {                                           \
            int row  = c * 32 + srow;                                           \
            int sseg = sseg0 ^ (row & 7);                                       \
            gll16(Bb + (size_t)row * (Kdim) + (k0) + sseg * 8,                  \
                  &Bsm[buf][(c * 256 + tid) * 8]);                              \
        }                                                                       \
    }

#define GEMM_KLOOP(Kdim)                                                        \
    GEMM_STAGE(0, 0, Kdim)                                                      \
    __syncthreads();                                                            \
    int cur = 0;                                                                \
    for (int k0 = 0; k0 < (Kdim); k0 += 64) {                                   \
        if (k0 + 64 < (Kdim)) GEMM_STAGE(cur ^ 1, k0 + 64, Kdim)                \
        _Pragma("unroll")                                                       \
        for (int ss = 0; ss < 2; ss++) {                                        \
            bf16x8 af[2], bfr[4];                                               \
            _Pragma("unroll")                                                   \
            for (int mi = 0; mi < 2; mi++) {                                    \
                int r = wm * 32 + mi * 16 + ll;                                 \
                int u = (ss * 4 + lg) ^ swl;                                    \
                af[mi] = *reinterpret_cast<const bf16x8*>(&Asm[cur][r * 64 + u * 8]); \
            }                                                                   \
            _Pragma("unroll")                                                   \
            for (int ni = 0; ni < 4; ni++) {                                    \
                int r = wn * 64 + ni * 16 + ll;                                 \
                int u = (ss * 4 + lg) ^ swl;                                    \
                bfr[ni] = *reinterpret_cast<const bf16x8*>(&Bsm[cur][r * 64 + u * 8]); \
            }                                                                   \
            _Pragma("unroll")                                                   \
            for (int mi = 0; mi < 2; mi++)                                      \
                _Pragma("unroll")                                               \
                for (int ni = 0; ni < 4; ni++)                                  \
                    acc[mi][ni] = __builtin_amdgcn_mfma_f32_16x16x32_bf16(      \
                        af[mi], bfr[ni], acc[mi][ni], 0, 0, 0);                 \
        }                                                                       \
        __syncthreads();                                                        \
        cur ^= 1;                                                               \
    }

// ---------------- GEMM2: C[M][N] = A * Bt^T, fp32 out ----------------
__global__ __launch_bounds__(256) void gemm_out(const __bf16* __restrict__ A,
                                                const __bf16* __restrict__ Bt,
                                                float* __restrict__ Cout,
                                                int M, int N, int K) {
    GEMM_PROLOGUE(A, Bt, K)
    GEMM_KLOOP(K)
    #pragma unroll
    for (int mi = 0; mi < 2; mi++)
        #pragma unroll
        for (int ni = 0; ni < 4; ni++)
            #pragma unroll
            for (int r = 0; r < 4; r++) {
                int row = bm + wm*32 + mi*16 + lg*4 + r;
                int col = bn + wn*64 + ni*16 + ll;
                Cout[(size_t)row * N + col] = acc[mi][ni][r];
            }
}

// ---------------- GEMM1 fused: qkv proj + RoPE + split + V-transpose ----------------
__global__ __launch_bounds__(256) void gemm_qkv(const __bf16* __restrict__ A,
                                                const __bf16* __restrict__ Bt,
                                                const int* __restrict__ pos,
                                                __bf16* __restrict__ q,
                                                __bf16* __restrict__ k,
                                                __bf16* __restrict__ vT) {
    GEMM_PROLOGUE(A, Bt, HIDDEN)
    GEMM_KLOOP(HIDDEN)

    if (bn < QSZ + KVSZ) {
        const bool isq = (bn < QSZ);
        const float ifr0 = exp2f((float)ll * -0.62286151779138f);
        const float ifr1 = exp2f((float)(16 + ll) * -0.62286151779138f);
        #pragma unroll
        for (int mi = 0; mi < 2; mi++) {
            #pragma unroll
            for (int r = 0; r < 4; r++) {
                int row = bm + wm*32 + mi*16 + lg*4 + r;
                float p = (float)pos[row];
                #pragma unroll
                for (int ni = 0; ni < 2; ni++) {
                    float ang = p * (ni ? ifr1 : ifr0);
                    float sn, cs;
                    sincosf(ang, &sn, &cs);
                    float x1 = acc[mi][ni][r], x2 = acc[mi][ni + 2][r];
                    float o1 = x1 * cs - x2 * sn;
                    float o2 = x2 * cs + x1 * sn;
                    int col = bn + wn*64 + ni*16 + ll;
                    if (isq) {
                        q[(size_t)row * QSZ + col]      = (__bf16)(o1 * QSCALE);
                        q[(size_t)row * QSZ + col + 32] = (__bf16)(o2 * QSCALE);
                    } else {
                        k[(size_t)row * KVSZ + (col - QSZ)]      = (__bf16)o1;
                        k[(size_t)row * KVSZ + (col - QSZ) + 32] = (__bf16)o2;
                    }
                }
            }
        }
    } else {
        #pragma unroll
        for (int mi = 0; mi < 2; mi++) {
            int row0 = bm + wm*32 + mi*16 + lg*4;
            #pragma unroll
            for (int ni = 0; ni < 4; ni++) {
                int d = bn + wn*64 + ni*16 + ll - (QSZ + KVSZ);
                bf16x4 pk;
                #pragma unroll
                for (int r = 0; r < 4; r++) pk[r] = (__bf16)acc[mi][ni][r];
                *reinterpret_cast<bf16x4*>(&vT[(size_t)d * T_SEQ + row0]) = pk;
            }
        }
    }
}

// ---------------- sliding-window GQA flash attention ----------------
// 512 threads = 8 waves; 2 query-heads (same kv-head) per block, 64 q-rows.
// K staged with bit-permuted source rows so QK^T's S^T output is ALREADY in
// PV A-fragment key order -> P never touches LDS (in-register pack only).
__global__ __launch_bounds__(512) void attn_kernel(const __bf16* __restrict__ qg,
                                                   const __bf16* __restrict__ kgl,
                                                   const __bf16* __restrict__ vTg,
                                                   __bf16* __restrict__ og) {
    const int qb  = blockIdx.x;
    const int hp  = blockIdx.y;          // head pair 0..15
    const int kvh = hp >> 2;
    const int tid = threadIdx.x;
    const int wid = tid >> 6;            // 0..7
    const int h   = hp * 2 + (wid >> 2);
    const int l   = tid & 63;
    const int lg  = l >> 4;
    const int ll  = l & 15;
    const int i0  = qb * 64;
    const int qw  = i0 + (wid & 3) * 16;
    const int qi  = qw + ll;

    __shared__ __align__(16) __bf16 Ksm[2][64 * 64];
    __shared__ __align__(16) __bf16 VTs[2][64 * 64];

    bf16x8 qf[2];
    {
        const __bf16* qp = qg + (size_t)(qw + ll) * QSZ + h * 64 + lg * 8;
        qf[0] = *reinterpret_cast<const bf16x8*>(qp);
        qf[1] = *reinterpret_cast<const bf16x8*>(qp + 32);
    }

    f32x4 o[4];
    #pragma unroll
    for (int dn = 0; dn < 4; dn++) o[dn] = (f32x4){0.f, 0.f, 0.f, 0.f};
    float l_run = 0.f;

    int jlo = i0 - (WINDOW - 1); if (jlo < 0) jlo = 0;
    int t0v = jlo & ~63;
    int tend = i0 + 64;

    // ---- staging geometry ----
    // LDS dest row = srow (linear); K global source row = bit-permuted key so
    // that sub-tile kt, D-row 4lg+r holds key 32*(kt>>1) + 8*lg + 4*(kt&1) + r.
    const int srow = tid >> 3;                       // 0..63
    const int sg   = (tid & 7) ^ (srow & 7);
    const int krow = (srow & 35) | ((srow & 8) << 1) | ((srow & 4) << 1) | ((srow & 16) >> 2);
    const __bf16* kp = kgl + (size_t)krow * KVSZ + kvh * 64 + sg * 8;
    const __bf16* vp = vTg + (size_t)(kvh * 64 + srow) * T_SEQ + sg * 8;

#define ASTAGE(buf, t)                                      \
    {                                                       \
        gll16(kp + (size_t)(t) * KVSZ, &Ksm[buf][tid * 8]); \
        gll16(vp + (t),                &VTs[buf][tid * 8]); \
    }

    ASTAGE(0, t0v);
    __syncthreads();

    const int swl = ll & 7;
    const int u0 = (lg ^ swl) * 8;
    const int u1 = ((4 + lg) ^ swl) * 8;

    int cur = 0;
    for (int t = t0v; t < tend; t += 64) {
        if (t + 64 < tend) ASTAGE(cur ^ 1, t + 64);

        bool active = (t <= qw + 15) && (t + 63 >= qw - (WINDOW - 1));
        if (active) {
            f32x4 sT[4];
            __builtin_amdgcn_s_setprio(1);
            #pragma unroll
            for (int kt = 0; kt < 4; kt++) {
                sT[kt] = (f32x4){0.f, 0.f, 0.f, 0.f};
                bf16x8 kf0 = *reinterpret_cast<const bf16x8*>(&Ksm[cur][kt*1024 + ll*64 + u0]);
                sT[kt] = __builtin_amdgcn_mfma_f32_16x16x32_bf16(kf0, qf[0], sT[kt], 0, 0, 0);
                bf16x8 kf1 = *reinterpret_cast<const bf16x8*>(&Ksm[cur][kt*1024 + ll*64 + u1]);
                sT[kt] = __builtin_amdgcn_mfma_f32_16x16x32_bf16(kf1, qf[1], sT[kt], 0, 0, 0);
            }
            __builtin_amdgcn_s_setprio(0);

            // softmax (no running max; normalization cancels the constant).
            // key held at sT[kt][r] = t + 32*(kt>>1) + 8*lg + 4*(kt&1) + r
            bool full = (t + 63 <= qw) && (t >= qw + 15 - (WINDOW - 1));
            float ts = 0.f;
            if (full) {
                #pragma unroll
                for (int kt = 0; kt < 4; kt++) {
                    #pragma unroll
                    for (int r = 0; r < 4; r++) {
                        float p = EXPS(sT[kt][r]);
                        sT[kt][r] = p;
                        ts += p;
                    }
                }
            } else {
                #pragma unroll
                for (int kt = 0; kt < 4; kt++) {
                    int jb = t + ((kt & 2) << 4) + ((kt & 1) << 2) + (lg << 3);
                    #pragma unroll
                    for (int r = 0; r < 4; r++) {
                        int j = jb + r;
                        bool ok = (j <= qi) && (qi - j < WINDOW);
                        float p = ok ? EXPS(sT[kt][r]) : 0.f;
                        sT[kt][r] = p;
                        ts += p;
                    }
                }
            }
            ts += __shfl_xor(ts, 16);
            ts += __shfl_xor(ts, 32);
            l_run += ts;

            __builtin_amdgcn_s_setprio(1);
            #pragma unroll
            for (int kt2 = 0; kt2 < 2; kt2++) {
                bf16x8 pa;
                #pragma unroll
                for (int r = 0; r < 4; r++) {
                    pa[r]     = (__bf16)sT[kt2*2][r];
                    pa[r + 4] = (__bf16)sT[kt2*2 + 1][r];
                }
                int uv = kt2 ? u1 : u0;
                #pragma unroll
                for (int dn = 0; dn < 4; dn++) {
                    bf16x8 vf = *reinterpret_cast<const bf16x8*>(&VTs[cur][dn*1024 + ll*64 + uv]);
                    o[dn] = __builtin_amdgcn_mfma_f32_16x16x32_bf16(pa, vf, o[dn], 0, 0, 0);
                }
            }
            __builtin_amdgcn_s_setprio(0);
        }
        __syncthreads();
        cur ^= 1;
    }
#undef ASTAGE

    float linv = 1.0f / l_run;
    float i0v = __shfl(linv, lg*4 + 0);
    float i1v = __shfl(linv, lg*4 + 1);
    float i2v = __shfl(linv, lg*4 + 2);
    float i3v = __shfl(linv, lg*4 + 3);
    #pragma unroll
    for (int dn = 0; dn < 4; dn++) {
        og[(size_t)(qw + lg*4 + 0) * QSZ + h*64 + dn*16 + ll] = (__bf16)(o[dn][0] * i0v);
        og[(size_t)(qw + lg*4 + 1) * QSZ + h*64 + dn*16 + ll] = (__bf16)(o[dn][1] * i1v);
        og[(size_t)(qw + lg*4 + 2) * QSZ + h*64 + dn*16 + ll] = (__bf16)(o[dn][2] * i2v);
        og[(size_t)(qw + lg*4 + 3) * QSZ + h*64 + dn*16 + ll] = (__bf16)(o[dn][3] * i3v);
    }
}

// ---------------- launch ----------------
extern "C" void kernel_launch(void* const* d_in, const int* in_sizes, int n_in,
                              void* d_out, int out_size, void* d_ws, size_t ws_size,
                              hipStream_t stream) {
    const int*   positions = (const int*)d_in[0];
    const float* hidden    = (const float*)d_in[1];
    const float* wqkv      = (const float*)d_in[2];
    const float* wo        = (const float*)d_in[3];
    float* out = (float*)d_out;

    char* ws = (char*)d_ws;
    __bf16* hidden_bf = (__bf16*)(ws);                       // 2048x2048
    __bf16* wqkv_t    = (__bf16*)(ws + 8388608);             // 2560x2048
    __bf16* wo_t      = (__bf16*)(ws + 18874368);            // 2048x2048
    __bf16* q_bf      = (__bf16*)(ws + 37748736);            // 2048x2048
    __bf16* k_bf      = (__bf16*)(ws + 46137344);            // 2048x256
    __bf16* vT_bf     = (__bf16*)(ws + 47185920);            // 256x2048 (V^T)
    __bf16* attn_bf   = (__bf16*)(ws + 48234496);            // 2048x2048

    cvt_f32_bf16<<<dim3((T_SEQ * HIDDEN) / 4 / 256), dim3(256), 0, stream>>>(
        (const float4*)hidden, (bf16x4*)hidden_bf);
    transpose_f32_bf16<<<dim3(QKVN / 32, HIDDEN / 32), dim3(256), 0, stream>>>(
        wqkv, wqkv_t, HIDDEN, QKVN);
    transpose_f32_bf16<<<dim3(HIDDEN / 32, QSZ / 32), dim3(256), 0, stream>>>(
        wo, wo_t, QSZ, HIDDEN);

    gemm_qkv<<<dim3(QKVN / 128, T_SEQ / 64), dim3(256), 0, stream>>>(
        hidden_bf, wqkv_t, positions, q_bf, k_bf, vT_bf);

    attn_kernel<<<dim3(T_SEQ / 64, 16), dim3(512), 0, stream>>>(
        q_bf, k_bf, vT_bf, attn_bf);

    gemm_out<<<dim3(HIDDEN / 128, T_SEQ / 64), dim3(256), 0, stream>>>(
        attn_bf, wo_t, out, T_SEQ, HIDDEN, QSZ);
}

// Round 9
// 109.904 us; speedup vs baseline: 1.3150x; 1.0318x over previous
//
#include <hip/hip_runtime.h>
#include <hip/hip_bf16.h>

// ---- types ----
typedef float  f32x4  __attribute__((ext_vector_type(4)));
typedef __bf16 bf16x8 __attribute__((ext_vector_type(8)));
typedef __bf16 bf16x4 __attribute__((ext_vector_type(4)));
typedef __bf16 bf16x2 __attribute__((ext_vector_type(2)));

#define T_SEQ   2048
#define HIDDEN  2048
#define NH      32
#define NKV     4
#define HD      64
#define QSZ     2048
#define KVSZ    256
#define QKVN    2560
#define WINDOW  1024

// raw v_exp_f32 if available (log2-domain scores); else __expf (natural domain)
#if __has_builtin(__builtin_amdgcn_exp2f)
#define EXPS(x) __builtin_amdgcn_exp2f(x)
#define QSCALE  0.1803368801111f   /* 0.125 * log2(e) */
#else
#define EXPS(x) __expf(x)
#define QSCALE  0.125f
#endif

__device__ __forceinline__ void gll16(const __bf16* g, __bf16* l) {
    __builtin_amdgcn_global_load_lds(
        (const __attribute__((address_space(1))) void*)g,
        (__attribute__((address_space(3))) void*)l,
        16, 0, 0);
}

// ================= fused prep kernel =================
// blocks [0,4096): hidden f32 -> bf16
// blocks [4096,4352): rope cos/sin table  tab[row*32+f] = {cos, sin}
// blocks [4352,5632): transpose wqkv [2048][2560] -> bf16 [2560][2048]
// blocks [5632,6656): transpose wo   [2048][2048] -> bf16 [2048][2048]
__global__ __launch_bounds__(256) void prep(const float4* __restrict__ hidden4,
                                            bf16x4* __restrict__ hidden_bf4,
                                            const float* __restrict__ wqkv,
                                            const float* __restrict__ wo,
                                            __bf16* __restrict__ wqkv_t,
                                            __bf16* __restrict__ wo_t,
                                            const int* __restrict__ pos,
                                            float2* __restrict__ ropetab) {
    __shared__ float tile[32][132];
    const int b = blockIdx.x;
    const int tid = threadIdx.x;

    if (b < 4096) {
        int id = b * 256 + tid;
        float4 v = hidden4[id];
        bf16x4 o;
        o[0] = (__bf16)v.x; o[1] = (__bf16)v.y; o[2] = (__bf16)v.z; o[3] = (__bf16)v.w;
        hidden_bf4[id] = o;
        return;
    }
    if (b < 4352) {
        int id = (b - 4096) * 256 + tid;      // 0..65535
        int row = id >> 5, f = id & 31;
        float p = (float)pos[row];
        float ifr = exp2f((float)f * -0.62286151779138f);
        float sn, cs;
        sincosf(p * ifr, &sn, &cs);
        ropetab[id] = make_float2(cs, sn);
        return;
    }

    // ---- transpose: tile 32 rows x 128 cols, float4 loads, bf16x4 stores ----
    const float* in;
    __bf16* out;
    int Rin, Cin, bx, by;
    if (b < 5632) {
        int t = b - 4352;                     // 0..1279 = 20 c-tiles x 64 r-tiles
        in = wqkv; out = wqkv_t; Rin = 2048; Cin = 2560;
        bx = t % 20; by = t / 20;
    } else {
        int t = b - 5632;                     // 0..1023 = 16 x 64
        in = wo; out = wo_t; Rin = 2048; Cin = 2048;
        bx = t % 16; by = t / 16;
    }
    const int ri = by * 32, ci = bx * 128;
    const int r0 = tid >> 5;                  // 0..7
    const int c4 = tid & 31;
    #pragma unroll
    for (int i = 0; i < 4; i++) {
        float4 v = *reinterpret_cast<const float4*>(
            &in[(size_t)(ri + r0 + i * 8) * Cin + ci + c4 * 4]);
        *reinterpret_cast<float4*>(&tile[r0 + i * 8][c4 * 4]) = v;
    }
    __syncthreads();
    const int c  = tid >> 3;                  // 0..31
    const int rb = tid & 7;                   // 0..7
    #pragma unroll
    for (int j = 0; j < 4; j++) {
        int cc = c + j * 32;
        bf16x4 pk;
        #pragma unroll
        for (int i = 0; i < 4; i++) pk[i] = (__bf16)tile[rb * 4 + i][cc];
        *reinterpret_cast<bf16x4*>(&out[(size_t)(ci + cc) * Rin + ri + rb * 4]) = pk;
    }
}

// ================= GEMM core (shared macros) =================
// Tile 64(M) x 128(N), 256 threads = 4 waves, wave tile 32x64.
// 2-phase double-buffered K-loop; gll16 staging; XOR-swizzled source & read.

#define GEMM_PROLOGUE(Aptr, Btptr, Kdim)                                        \
    __shared__ __align__(16) __bf16 Asm[2][64 * 64];                            \
    __shared__ __align__(16) __bf16 Bsm[2][128 * 64];                           \
    const int tid = threadIdx.x;                                                \
    const int wid = tid >> 6;                                                   \
    const int l   = tid & 63;                                                   \
    const int lg  = l >> 4;                                                     \
    const int ll  = l & 15;                                                     \
    const int swl = ll & 7;                                                     \
    const int wm  = wid >> 1, wn = wid & 1;                                     \
    const int gx   = gridDim.x;                                                 \
    const int flat = blockIdx.y * gx + blockIdx.x;                              \
    const int nwg  = gx * gridDim.y;                                            \
    const int swz  = (flat & 7) * (nwg >> 3) + (flat >> 3);                     \
    const int bm   = (swz / gx) * 64;                                           \
    const int bn   = (swz % gx) * 128;                                          \
    const __bf16* Ab = (Aptr) + (size_t)bm * (Kdim);                            \
    const __bf16* Bb = (Btptr) + (size_t)bn * (Kdim);                           \
    f32x4 acc[2][4];                                                            \
    _Pragma("unroll")                                                           \
    for (int i = 0; i < 2; i++)                                                 \
        _Pragma("unroll")                                                       \
        for (int j = 0; j < 4; j++)                                             \
            acc[i][j] = (f32x4){0.f, 0.f, 0.f, 0.f};                            \
    const int srow = tid >> 3;                                                  \
    const int sseg0 = tid & 7;

#define GEMM_STAGE(buf, k0, Kdim)                                               \
    {                                                                           \
        _Pragma("unroll")                                                       \
        for (int c = 0; c < 2; c++) {                                           \
            int row  = c * 32 + srow;                                           \
            int sseg = sseg0 ^ (row & 7);                                       \
            gll16(Ab + (size_t)row * (Kdim) + (k0) + sseg * 8,                  \
                  &Asm[buf][(c * 256 + tid) * 8]);                              \
        }                                                                       \
        _Pragma("unroll")                                                       \
        for (int c = 0; c < 4; c++) {                                           \
            int row  = c * 32 + srow;                                           \
            int sseg = sseg0 ^ (row & 7);                                       \
            gll16(Bb + (size_t)row * (Kdim) + (k0) + sseg * 8,                  \
                  &Bsm[buf][(c * 256 + tid) * 8]);                              \
        }                                                                       \
    }

#define GEMM_KLOOP(Kdim)                                                        \
    GEMM_STAGE(0, 0, Kdim)                                                      \
    __syncthreads();                                                            \
    int cur = 0;                                                                \
    for (int k0 = 0; k0 < (Kdim); k0 += 64) {                                   \
        if (k0 + 64 < (Kdim)) GEMM_STAGE(cur ^ 1, k0 + 64, Kdim)                \
        _Pragma("unroll")                                                       \
        for (int ss = 0; ss < 2; ss++) {                                        \
            bf16x8 af[2], bfr[4];                                               \
            _Pragma("unroll")                                                   \
            for (int mi = 0; mi < 2; mi++) {                                    \
                int r = wm * 32 + mi * 16 + ll;                                 \
                int u = (ss * 4 + lg) ^ swl;                                    \
                af[mi] = *reinterpret_cast<const bf16x8*>(&Asm[cur][r * 64 + u * 8]); \
            }                                                                   \
            _Pragma("unroll")                                                   \
            for (int ni = 0; ni < 4; ni++) {                                    \
                int r = wn * 64 + ni * 16 + ll;                                 \
                int u = (ss * 4 + lg) ^ swl;                                    \
                bfr[ni] = *reinterpret_cast<const bf16x8*>(&Bsm[cur][r * 64 + u * 8]); \
            }                                                                   \
            _Pragma("unroll")                                                   \
            for (int mi = 0; mi < 2; mi++)                                      \
                _Pragma("unroll")                                               \
                for (int ni = 0; ni < 4; ni++)                                  \
                    acc[mi][ni] = __builtin_amdgcn_mfma_f32_16x16x32_bf16(      \
                        af[mi], bfr[ni], acc[mi][ni], 0, 0, 0);                 \
        }                                                                       \
        __syncthreads();                                                        \
        cur ^= 1;                                                               \
    }

// ---------------- GEMM2: C[M][N] = A * Bt^T, fp32 out ----------------
__global__ __launch_bounds__(256) void gemm_out(const __bf16* __restrict__ A,
                                                const __bf16* __restrict__ Bt,
                                                float* __restrict__ Cout,
                                                int M, int N, int K) {
    GEMM_PROLOGUE(A, Bt, K)
    GEMM_KLOOP(K)
    #pragma unroll
    for (int mi = 0; mi < 2; mi++)
        #pragma unroll
        for (int ni = 0; ni < 4; ni++)
            #pragma unroll
            for (int r = 0; r < 4; r++) {
                int row = bm + wm*32 + mi*16 + lg*4 + r;
                int col = bn + wn*64 + ni*16 + ll;
                Cout[(size_t)row * N + col] = acc[mi][ni][r];
            }
}

// ---------------- GEMM1 fused: qkv proj + RoPE(table) + split + V-transpose ----------------
__global__ __launch_bounds__(256) void gemm_qkv(const __bf16* __restrict__ A,
                                                const __bf16* __restrict__ Bt,
                                                const float2* __restrict__ ropetab,
                                                __bf16* __restrict__ q,
                                                __bf16* __restrict__ k,
                                                __bf16* __restrict__ vT) {
    GEMM_PROLOGUE(A, Bt, HIDDEN)
    GEMM_KLOOP(HIDDEN)

    if (bn < QSZ + KVSZ) {
        const bool isq = (bn < QSZ);
        #pragma unroll
        for (int mi = 0; mi < 2; mi++) {
            #pragma unroll
            for (int r = 0; r < 4; r++) {
                int row = bm + wm*32 + mi*16 + lg*4 + r;
                const float2* tb = &ropetab[row * 32 + ll];
                #pragma unroll
                for (int ni = 0; ni < 2; ni++) {
                    float2 cssn = tb[ni * 16];
                    float x1 = acc[mi][ni][r], x2 = acc[mi][ni + 2][r];
                    float o1 = x1 * cssn.x - x2 * cssn.y;
                    float o2 = x2 * cssn.x + x1 * cssn.y;
                    int col = bn + wn*64 + ni*16 + ll;
                    if (isq) {
                        q[(size_t)row * QSZ + col]      = (__bf16)(o1 * QSCALE);
                        q[(size_t)row * QSZ + col + 32] = (__bf16)(o2 * QSCALE);
                    } else {
                        k[(size_t)row * KVSZ + (col - QSZ)]      = (__bf16)o1;
                        k[(size_t)row * KVSZ + (col - QSZ) + 32] = (__bf16)o2;
                    }
                }
            }
        }
    } else {
        #pragma unroll
        for (int mi = 0; mi < 2; mi++) {
            int row0 = bm + wm*32 + mi*16 + lg*4;
            #pragma unroll
            for (int ni = 0; ni < 4; ni++) {
                int d = bn + wn*64 + ni*16 + ll - (QSZ + KVSZ);
                bf16x4 pk;
                #pragma unroll
                for (int r = 0; r < 4; r++) pk[r] = (__bf16)acc[mi][ni][r];
                *reinterpret_cast<bf16x4*>(&vT[(size_t)d * T_SEQ + row0]) = pk;
            }
        }
    }
}

// ---------------- sliding-window GQA flash attention ----------------
// 512 threads = 8 waves; 2 query-heads (same kv-head) per block, 64 q-rows.
// K staged with bit-permuted source rows so QK^T's S^T output is ALREADY in
// PV A-fragment key order -> P never touches LDS (in-register pack only).
__global__ __launch_bounds__(512) void attn_kernel(const __bf16* __restrict__ qg,
                                                   const __bf16* __restrict__ kgl,
                                                   const __bf16* __restrict__ vTg,
                                                   __bf16* __restrict__ og) {
    const int qb  = blockIdx.x;
    const int hp  = blockIdx.y;          // head pair 0..15
    const int kvh = hp >> 2;
    const int tid = threadIdx.x;
    const int wid = tid >> 6;            // 0..7
    const int h   = hp * 2 + (wid >> 2);
    const int l   = tid & 63;
    const int lg  = l >> 4;
    const int ll  = l & 15;
    const int i0  = qb * 64;
    const int qw  = i0 + (wid & 3) * 16;
    const int qi  = qw + ll;

    __shared__ __align__(16) __bf16 Ksm[2][64 * 64];
    __shared__ __align__(16) __bf16 VTs[2][64 * 64];

    bf16x8 qf[2];
    {
        const __bf16* qp = qg + (size_t)(qw + ll) * QSZ + h * 64 + lg * 8;
        qf[0] = *reinterpret_cast<const bf16x8*>(qp);
        qf[1] = *reinterpret_cast<const bf16x8*>(qp + 32);
    }

    f32x4 o[4];
    #pragma unroll
    for (int dn = 0; dn < 4; dn++) o[dn] = (f32x4){0.f, 0.f, 0.f, 0.f};
    float l_run = 0.f;

    int jlo = i0 - (WINDOW - 1); if (jlo < 0) jlo = 0;
    int t0v = jlo & ~63;
    int tend = i0 + 64;

    const int srow = tid >> 3;                       // 0..63
    const int sg   = (tid & 7) ^ (srow & 7);
    const int krow = (srow & 35) | ((srow & 8) << 1) | ((srow & 4) << 1) | ((srow & 16) >> 2);
    const __bf16* kp = kgl + (size_t)krow * KVSZ + kvh * 64 + sg * 8;
    const __bf16* vp = vTg + (size_t)(kvh * 64 + srow) * T_SEQ + sg * 8;

#define ASTAGE(buf, t)                                      \
    {                                                       \
        gll16(kp + (size_t)(t) * KVSZ, &Ksm[buf][tid * 8]); \
        gll16(vp + (t),                &VTs[buf][tid * 8]); \
    }

    ASTAGE(0, t0v);
    __syncthreads();

    const int swl = ll & 7;
    const int u0 = (lg ^ swl) * 8;
    const int u1 = ((4 + lg) ^ swl) * 8;

    int cur = 0;
    for (int t = t0v; t < tend; t += 64) {
        if (t + 64 < tend) ASTAGE(cur ^ 1, t + 64);

        bool active = (t <= qw + 15) && (t + 63 >= qw - (WINDOW - 1));
        if (active) {
            f32x4 sT[4];
            __builtin_amdgcn_s_setprio(1);
            #pragma unroll
            for (int kt = 0; kt < 4; kt++) {
                sT[kt] = (f32x4){0.f, 0.f, 0.f, 0.f};
                bf16x8 kf0 = *reinterpret_cast<const bf16x8*>(&Ksm[cur][kt*1024 + ll*64 + u0]);
                sT[kt] = __builtin_amdgcn_mfma_f32_16x16x32_bf16(kf0, qf[0], sT[kt], 0, 0, 0);
                bf16x8 kf1 = *reinterpret_cast<const bf16x8*>(&Ksm[cur][kt*1024 + ll*64 + u1]);
                sT[kt] = __builtin_amdgcn_mfma_f32_16x16x32_bf16(kf1, qf[1], sT[kt], 0, 0, 0);
            }
            __builtin_amdgcn_s_setprio(0);

            // softmax (no running max; normalization cancels the constant).
            // key held at sT[kt][r] = t + 32*(kt>>1) + 8*lg + 4*(kt&1) + r
            bool full = (t + 63 <= qw) && (t >= qw + 15 - (WINDOW - 1));
            float ts = 0.f;
            if (full) {
                #pragma unroll
                for (int kt = 0; kt < 4; kt++) {
                    #pragma unroll
                    for (int r = 0; r < 4; r++) {
                        float p = EXPS(sT[kt][r]);
                        sT[kt][r] = p;
                        ts += p;
                    }
                }
            } else {
                #pragma unroll
                for (int kt = 0; kt < 4; kt++) {
                    int jb = t + ((kt & 2) << 4) + ((kt & 1) << 2) + (lg << 3);
                    #pragma unroll
                    for (int r = 0; r < 4; r++) {
                        int j = jb + r;
                        bool ok = (j <= qi) && (qi - j < WINDOW);
                        float p = ok ? EXPS(sT[kt][r]) : 0.f;
                        sT[kt][r] = p;
                        ts += p;
                    }
                }
            }
            ts += __shfl_xor(ts, 16);
            ts += __shfl_xor(ts, 32);
            l_run += ts;

            __builtin_amdgcn_s_setprio(1);
            #pragma unroll
            for (int kt2 = 0; kt2 < 2; kt2++) {
                bf16x8 pa;
                #pragma unroll
                for (int r = 0; r < 4; r++) {
                    pa[r]     = (__bf16)sT[kt2*2][r];
                    pa[r + 4] = (__bf16)sT[kt2*2 + 1][r];
                }
                int uv = kt2 ? u1 : u0;
                #pragma unroll
                for (int dn = 0; dn < 4; dn++) {
                    bf16x8 vf = *reinterpret_cast<const bf16x8*>(&VTs[cur][dn*1024 + ll*64 + uv]);
                    o[dn] = __builtin_amdgcn_mfma_f32_16x16x32_bf16(pa, vf, o[dn], 0, 0, 0);
                }
            }
            __builtin_amdgcn_s_setprio(0);
        }
        __syncthreads();
        cur ^= 1;
    }
#undef ASTAGE

    float linv = 1.0f / l_run;
    float i0v = __shfl(linv, lg*4 + 0);
    float i1v = __shfl(linv, lg*4 + 1);
    float i2v = __shfl(linv, lg*4 + 2);
    float i3v = __shfl(linv, lg*4 + 3);
    #pragma unroll
    for (int dn = 0; dn < 4; dn++) {
        og[(size_t)(qw + lg*4 + 0) * QSZ + h*64 + dn*16 + ll] = (__bf16)(o[dn][0] * i0v);
        og[(size_t)(qw + lg*4 + 1) * QSZ + h*64 + dn*16 + ll] = (__bf16)(o[dn][1] * i1v);
        og[(size_t)(qw + lg*4 + 2) * QSZ + h*64 + dn*16 + ll] = (__bf16)(o[dn][2] * i2v);
        og[(size_t)(qw + lg*4 + 3) * QSZ + h*64 + dn*16 + ll] = (__bf16)(o[dn][3] * i3v);
    }
}

// ---------------- launch ----------------
extern "C" void kernel_launch(void* const* d_in, const int* in_sizes, int n_in,
                              void* d_out, int out_size, void* d_ws, size_t ws_size,
                              hipStream_t stream) {
    const int*   positions = (const int*)d_in[0];
    const float* hidden    = (const float*)d_in[1];
    const float* wqkv      = (const float*)d_in[2];
    const float* wo        = (const float*)d_in[3];
    float* out = (float*)d_out;

    char* ws = (char*)d_ws;
    __bf16* hidden_bf = (__bf16*)(ws);                       // 2048x2048
    __bf16* wqkv_t    = (__bf16*)(ws + 8388608);             // 2560x2048
    __bf16* wo_t      = (__bf16*)(ws + 18874368);            // 2048x2048
    __bf16* q_bf      = (__bf16*)(ws + 37748736);            // 2048x2048
    __bf16* k_bf      = (__bf16*)(ws + 46137344);            // 2048x256
    __bf16* vT_bf     = (__bf16*)(ws + 47185920);            // 256x2048 (V^T)
    __bf16* attn_bf   = (__bf16*)(ws + 48234496);            // 2048x2048
    float2* ropetab   = (float2*)(ws + 56623104);            // 2048x32 float2

    prep<<<dim3(6656), dim3(256), 0, stream>>>(
        (const float4*)hidden, (bf16x4*)hidden_bf, wqkv, wo,
        wqkv_t, wo_t, positions, ropetab);

    gemm_qkv<<<dim3(QKVN / 128, T_SEQ / 64), dim3(256), 0, stream>>>(
        hidden_bf, wqkv_t, ropetab, q_bf, k_bf, vT_bf);

    attn_kernel<<<dim3(T_SEQ / 64, 16), dim3(512), 0, stream>>>(
        q_bf, k_bf, vT_bf, attn_bf);

    gemm_out<<<dim3(HIDDEN / 128, T_SEQ / 64), dim3(256), 0, stream>>>(
        attn_bf, wo_t, out, T_SEQ, HIDDEN, QSZ);
}

// Round 10
// 106.665 us; speedup vs baseline: 1.3549x; 1.0304x over previous
//
#include <hip/hip_runtime.h>
#include <hip/hip_bf16.h>

// ---- types ----
typedef float  f32x4  __attribute__((ext_vector_type(4)));
typedef __bf16 bf16x8 __attribute__((ext_vector_type(8)));
typedef __bf16 bf16x4 __attribute__((ext_vector_type(4)));
typedef __bf16 bf16x2 __attribute__((ext_vector_type(2)));

#define T_SEQ   2048
#define HIDDEN  2048
#define NH      32
#define NKV     4
#define HD      64
#define QSZ     2048
#define KVSZ    256
#define QKVN    2560
#define WINDOW  1024

// raw v_exp_f32 if available (log2-domain scores); else __expf (natural domain)
#if __has_builtin(__builtin_amdgcn_exp2f)
#define EXPS(x) __builtin_amdgcn_exp2f(x)
#define QSCALE  0.1803368801111f   /* 0.125 * log2(e) */
#else
#define EXPS(x) __expf(x)
#define QSCALE  0.125f
#endif

#define RAW_BARRIER()   asm volatile("s_barrier" ::: "memory")
#define WAITV(n)        asm volatile("s_waitcnt vmcnt(" #n ")" ::: "memory")

__device__ __forceinline__ void gll16(const __bf16* g, __bf16* l) {
    __builtin_amdgcn_global_load_lds(
        (const __attribute__((address_space(1))) void*)g,
        (__attribute__((address_space(3))) void*)l,
        16, 0, 0);
}

// ================= fused prep kernel =================
// blocks [0,4096): hidden f32 -> bf16
// blocks [4096,4352): rope cos/sin table  tab[row*32+f] = {cos, sin}
// blocks [4352,5632): transpose wqkv [2048][2560] -> bf16 [2560][2048]
// blocks [5632,6656): transpose wo   [2048][2048] -> bf16 [2048][2048]
__global__ __launch_bounds__(256) void prep(const float4* __restrict__ hidden4,
                                            bf16x4* __restrict__ hidden_bf4,
                                            const float* __restrict__ wqkv,
                                            const float* __restrict__ wo,
                                            __bf16* __restrict__ wqkv_t,
                                            __bf16* __restrict__ wo_t,
                                            const int* __restrict__ pos,
                                            float2* __restrict__ ropetab) {
    __shared__ float tile[32][132];
    const int b = blockIdx.x;
    const int tid = threadIdx.x;

    if (b < 4096) {
        int id = b * 256 + tid;
        float4 v = hidden4[id];
        bf16x4 o;
        o[0] = (__bf16)v.x; o[1] = (__bf16)v.y; o[2] = (__bf16)v.z; o[3] = (__bf16)v.w;
        hidden_bf4[id] = o;
        return;
    }
    if (b < 4352) {
        int id = (b - 4096) * 256 + tid;      // 0..65535
        int row = id >> 5, f = id & 31;
        float p = (float)pos[row];
        float ifr = exp2f((float)f * -0.62286151779138f);
        float sn, cs;
        sincosf(p * ifr, &sn, &cs);
        ropetab[id] = make_float2(cs, sn);
        return;
    }

    // ---- transpose: tile 32 rows x 128 cols, float4 loads, bf16x4 stores ----
    const float* in;
    __bf16* out;
    int Rin, Cin, bx, by;
    if (b < 5632) {
        int t = b - 4352;                     // 0..1279 = 20 c-tiles x 64 r-tiles
        in = wqkv; out = wqkv_t; Rin = 2048; Cin = 2560;
        bx = t % 20; by = t / 20;
    } else {
        int t = b - 5632;                     // 0..1023 = 16 x 64
        in = wo; out = wo_t; Rin = 2048; Cin = 2048;
        bx = t % 16; by = t / 16;
    }
    const int ri = by * 32, ci = bx * 128;
    const int r0 = tid >> 5;                  // 0..7
    const int c4 = tid & 31;
    #pragma unroll
    for (int i = 0; i < 4; i++) {
        float4 v = *reinterpret_cast<const float4*>(
            &in[(size_t)(ri + r0 + i * 8) * Cin + ci + c4 * 4]);
        *reinterpret_cast<float4*>(&tile[r0 + i * 8][c4 * 4]) = v;
    }
    __syncthreads();
    const int c  = tid >> 3;                  // 0..31
    const int rb = tid & 7;                   // 0..7
    #pragma unroll
    for (int j = 0; j < 4; j++) {
        int cc = c + j * 32;
        bf16x4 pk;
        #pragma unroll
        for (int i = 0; i < 4; i++) pk[i] = (__bf16)tile[rb * 4 + i][cc];
        *reinterpret_cast<bf16x4*>(&out[(size_t)(ci + cc) * Rin + ri + rb * 4]) = pk;
    }
}

// ================= GEMM core (shared macros) =================
// Tile 64(M) x 128(N), 256 threads = 4 waves, wave tile 32x64.
// 2-buffer K-loop with COUNTED vmcnt (no full drain): barrierA(read-done) ->
// issue stage(next) -> vmcnt(6) -> barrierB(data-ready) -> compute.

#define GEMM_PROLOGUE(Aptr, Btptr, Kdim)                                        \
    __shared__ __align__(16) __bf16 Asm[2][64 * 64];                            \
    __shared__ __align__(16) __bf16 Bsm[2][128 * 64];                           \
    const int tid = threadIdx.x;                                                \
    const int wid = tid >> 6;                                                   \
    const int l   = tid & 63;                                                   \
    const int lg  = l >> 4;                                                     \
    const int ll  = l & 15;                                                     \
    const int swl = ll & 7;                                                     \
    const int wm  = wid >> 1, wn = wid & 1;                                     \
    const int gx   = gridDim.x;                                                 \
    const int flat = blockIdx.y * gx + blockIdx.x;                              \
    const int nwg  = gx * gridDim.y;                                            \
    const int swz  = (flat & 7) * (nwg >> 3) + (flat >> 3);                     \
    const int bm   = (swz / gx) * 64;                                           \
    const int bn   = (swz % gx) * 128;                                          \
    const __bf16* Ab = (Aptr) + (size_t)bm * (Kdim);                            \
    const __bf16* Bb = (Btptr) + (size_t)bn * (Kdim);                           \
    f32x4 acc[2][4];                                                            \
    _Pragma("unroll")                                                           \
    for (int i = 0; i < 2; i++)                                                 \
        _Pragma("unroll")                                                       \
        for (int j = 0; j < 4; j++)                                             \
            acc[i][j] = (f32x4){0.f, 0.f, 0.f, 0.f};                            \
    const int srow = tid >> 3;                                                  \
    const int sseg0 = tid & 7;

#define GEMM_STAGE(buf, k0, Kdim)                                               \
    {                                                                           \
        _Pragma("unroll")                                                       \
        for (int c = 0; c < 2; c++) {                                           \
            int row  = c * 32 + srow;                                           \
            int sseg = sseg0 ^ (row & 7);                                       \
            gll16(Ab + (size_t)row * (Kdim) + (k0) + sseg * 8,                  \
                  &Asm[buf][(c * 256 + tid) * 8]);                              \
        }                                                                       \
        _Pragma("unroll")                                                       \
        for (int c = 0; c < 4; c++) {                                           \
            int row  = c * 32 + srow;                                           \
            int sseg = sseg0 ^ (row & 7);                                       \
            gll16(Bb + (size_t)row * (Kdim) + (k0) + sseg * 8,                  \
                  &Bsm[buf][(c * 256 + tid) * 8]);                              \
        }                                                                       \
    }

#define GEMM_KLOOP(Kdim)                                                        \
    GEMM_STAGE(0, 0, Kdim)                                                      \
    int cur = 0;                                                                \
    for (int k0 = 0; k0 < (Kdim); k0 += 64) {                                   \
        RAW_BARRIER();               /* read-done for buffer being overwritten */\
        if (k0 + 64 < (Kdim)) {                                                 \
            GEMM_STAGE(cur ^ 1, k0 + 64, Kdim)                                  \
            WAITV(6);                /* this tile's 6 loads done; 6 in flight */ \
        } else {                                                                \
            WAITV(0);                                                           \
        }                                                                       \
        RAW_BARRIER();               /* data-ready across waves */              \
        __builtin_amdgcn_sched_barrier(0);                                      \
        _Pragma("unroll")                                                       \
        for (int ss = 0; ss < 2; ss++) {                                        \
            bf16x8 af[2], bfr[4];                                               \
            _Pragma("unroll")                                                   \
            for (int mi = 0; mi < 2; mi++) {                                    \
                int r = wm * 32 + mi * 16 + ll;                                 \
                int u = (ss * 4 + lg) ^ swl;                                    \
                af[mi] = *reinterpret_cast<const bf16x8*>(&Asm[cur][r * 64 + u * 8]); \
            }                                                                   \
            _Pragma("unroll")                                                   \
            for (int ni = 0; ni < 4; ni++) {                                    \
                int r = wn * 64 + ni * 16 + ll;                                 \
                int u = (ss * 4 + lg) ^ swl;                                    \
                bfr[ni] = *reinterpret_cast<const bf16x8*>(&Bsm[cur][r * 64 + u * 8]); \
            }                                                                   \
            _Pragma("unroll")                                                   \
            for (int mi = 0; mi < 2; mi++)                                      \
                _Pragma("unroll")                                               \
                for (int ni = 0; ni < 4; ni++)                                  \
                    acc[mi][ni] = __builtin_amdgcn_mfma_f32_16x16x32_bf16(      \
                        af[mi], bfr[ni], acc[mi][ni], 0, 0, 0);                 \
        }                                                                       \
        cur ^= 1;                                                               \
    }

// ---------------- GEMM2: C[M][N] = A * Bt^T, fp32 out ----------------
__global__ __launch_bounds__(256) void gemm_out(const __bf16* __restrict__ A,
                                                const __bf16* __restrict__ Bt,
                                                float* __restrict__ Cout,
                                                int M, int N, int K) {
    GEMM_PROLOGUE(A, Bt, K)
    GEMM_KLOOP(K)
    #pragma unroll
    for (int mi = 0; mi < 2; mi++)
        #pragma unroll
        for (int ni = 0; ni < 4; ni++)
            #pragma unroll
            for (int r = 0; r < 4; r++) {
                int row = bm + wm*32 + mi*16 + lg*4 + r;
                int col = bn + wn*64 + ni*16 + ll;
                Cout[(size_t)row * N + col] = acc[mi][ni][r];
            }
}

// ---------------- GEMM1 fused: qkv proj + RoPE(table) + split + V-transpose ----------------
__global__ __launch_bounds__(256) void gemm_qkv(const __bf16* __restrict__ A,
                                                const __bf16* __restrict__ Bt,
                                                const float2* __restrict__ ropetab,
                                                __bf16* __restrict__ q,
                                                __bf16* __restrict__ k,
                                                __bf16* __restrict__ vT) {
    GEMM_PROLOGUE(A, Bt, HIDDEN)
    GEMM_KLOOP(HIDDEN)

    if (bn < QSZ + KVSZ) {
        const bool isq = (bn < QSZ);
        #pragma unroll
        for (int mi = 0; mi < 2; mi++) {
            #pragma unroll
            for (int r = 0; r < 4; r++) {
                int row = bm + wm*32 + mi*16 + lg*4 + r;
                const float2* tb = &ropetab[row * 32 + ll];
                #pragma unroll
                for (int ni = 0; ni < 2; ni++) {
                    float2 cssn = tb[ni * 16];
                    float x1 = acc[mi][ni][r], x2 = acc[mi][ni + 2][r];
                    float o1 = x1 * cssn.x - x2 * cssn.y;
                    float o2 = x2 * cssn.x + x1 * cssn.y;
                    int col = bn + wn*64 + ni*16 + ll;
                    if (isq) {
                        q[(size_t)row * QSZ + col]      = (__bf16)(o1 * QSCALE);
                        q[(size_t)row * QSZ + col + 32] = (__bf16)(o2 * QSCALE);
                    } else {
                        k[(size_t)row * KVSZ + (col - QSZ)]      = (__bf16)o1;
                        k[(size_t)row * KVSZ + (col - QSZ) + 32] = (__bf16)o2;
                    }
                }
            }
        }
    } else {
        #pragma unroll
        for (int mi = 0; mi < 2; mi++) {
            int row0 = bm + wm*32 + mi*16 + lg*4;
            #pragma unroll
            for (int ni = 0; ni < 4; ni++) {
                int d = bn + wn*64 + ni*16 + ll - (QSZ + KVSZ);
                bf16x4 pk;
                #pragma unroll
                for (int r = 0; r < 4; r++) pk[r] = (__bf16)acc[mi][ni][r];
                *reinterpret_cast<bf16x4*>(&vT[(size_t)d * T_SEQ + row0]) = pk;
            }
        }
    }
}

// ---------------- sliding-window GQA flash attention ----------------
// 512 threads = 8 waves; 2 query-heads (same kv-head) per block, 64 q-rows.
// K staged with bit-permuted source rows so QK^T's S^T output is ALREADY in
// PV A-fragment key order -> P never touches LDS. Counted-vmcnt double buffer.
__global__ __launch_bounds__(512) void attn_kernel(const __bf16* __restrict__ qg,
                                                   const __bf16* __restrict__ kgl,
                                                   const __bf16* __restrict__ vTg,
                                                   __bf16* __restrict__ og) {
    const int qb  = blockIdx.x;
    const int hp  = blockIdx.y;          // head pair 0..15
    const int kvh = hp >> 2;
    const int tid = threadIdx.x;
    const int wid = tid >> 6;            // 0..7
    const int h   = hp * 2 + (wid >> 2);
    const int l   = tid & 63;
    const int lg  = l >> 4;
    const int ll  = l & 15;
    const int i0  = qb * 64;
    const int qw  = i0 + (wid & 3) * 16;
    const int qi  = qw + ll;

    __shared__ __align__(16) __bf16 Ksm[2][64 * 64];
    __shared__ __align__(16) __bf16 VTs[2][64 * 64];

    bf16x8 qf[2];
    {
        const __bf16* qp = qg + (size_t)(qw + ll) * QSZ + h * 64 + lg * 8;
        qf[0] = *reinterpret_cast<const bf16x8*>(qp);
        qf[1] = *reinterpret_cast<const bf16x8*>(qp + 32);
    }

    f32x4 o[4];
    #pragma unroll
    for (int dn = 0; dn < 4; dn++) o[dn] = (f32x4){0.f, 0.f, 0.f, 0.f};
    float l_run = 0.f;

    int jlo = i0 - (WINDOW - 1); if (jlo < 0) jlo = 0;
    int t0v = jlo & ~63;
    int tend = i0 + 64;

    const int srow = tid >> 3;                       // 0..63
    const int sg   = (tid & 7) ^ (srow & 7);
    const int krow = (srow & 35) | ((srow & 8) << 1) | ((srow & 4) << 1) | ((srow & 16) >> 2);
    const __bf16* kp = kgl + (size_t)krow * KVSZ + kvh * 64 + sg * 8;
    const __bf16* vp = vTg + (size_t)(kvh * 64 + srow) * T_SEQ + sg * 8;

#define ASTAGE(buf, t)                                      \
    {                                                       \
        gll16(kp + (size_t)(t) * KVSZ, &Ksm[buf][tid * 8]); \
        gll16(vp + (t),                &VTs[buf][tid * 8]); \
    }

    ASTAGE(0, t0v);

    const int swl = ll & 7;
    const int u0 = (lg ^ swl) * 8;
    const int u1 = ((4 + lg) ^ swl) * 8;

    int cur = 0;
    for (int t = t0v; t < tend; t += 64) {
        RAW_BARRIER();                 // read-done for buffer being overwritten
        if (t + 64 < tend) {
            ASTAGE(cur ^ 1, t + 64);
            WAITV(2);                  // this tile's 2 loads done; 2 in flight
        } else {
            WAITV(0);
        }
        RAW_BARRIER();                 // data-ready across waves
        __builtin_amdgcn_sched_barrier(0);

        bool active = (t <= qw + 15) && (t + 63 >= qw - (WINDOW - 1));
        if (active) {
            f32x4 sT[4];
            __builtin_amdgcn_s_setprio(1);
            #pragma unroll
            for (int kt = 0; kt < 4; kt++) {
                sT[kt] = (f32x4){0.f, 0.f, 0.f, 0.f};
                bf16x8 kf0 = *reinterpret_cast<const bf16x8*>(&Ksm[cur][kt*1024 + ll*64 + u0]);
                sT[kt] = __builtin_amdgcn_mfma_f32_16x16x32_bf16(kf0, qf[0], sT[kt], 0, 0, 0);
                bf16x8 kf1 = *reinterpret_cast<const bf16x8*>(&Ksm[cur][kt*1024 + ll*64 + u1]);
                sT[kt] = __builtin_amdgcn_mfma_f32_16x16x32_bf16(kf1, qf[1], sT[kt], 0, 0, 0);
            }
            __builtin_amdgcn_s_setprio(0);

            // softmax (no running max; normalization cancels the constant).
            // key held at sT[kt][r] = t + 32*(kt>>1) + 8*lg + 4*(kt&1) + r
            bool full = (t + 63 <= qw) && (t >= qw + 15 - (WINDOW - 1));
            float ts = 0.f;
            if (full) {
                #pragma unroll
                for (int kt = 0; kt < 4; kt++) {
                    #pragma unroll
                    for (int r = 0; r < 4; r++) {
                        float p = EXPS(sT[kt][r]);
                        sT[kt][r] = p;
                        ts += p;
                    }
                }
            } else {
                #pragma unroll
                for (int kt = 0; kt < 4; kt++) {
                    int jb = t + ((kt & 2) << 4) + ((kt & 1) << 2) + (lg << 3);
                    #pragma unroll
                    for (int r = 0; r < 4; r++) {
                        int j = jb + r;
                        bool ok = (j <= qi) && (qi - j < WINDOW);
                        float p = ok ? EXPS(sT[kt][r]) : 0.f;
                        sT[kt][r] = p;
                        ts += p;
                    }
                }
            }
            ts += __shfl_xor(ts, 16);
            ts += __shfl_xor(ts, 32);
            l_run += ts;

            __builtin_amdgcn_s_setprio(1);
            #pragma unroll
            for (int kt2 = 0; kt2 < 2; kt2++) {
                bf16x8 pa;
                #pragma unroll
                for (int r = 0; r < 4; r++) {
                    pa[r]     = (__bf16)sT[kt2*2][r];
                    pa[r + 4] = (__bf16)sT[kt2*2 + 1][r];
                }
                int uv = kt2 ? u1 : u0;
                #pragma unroll
                for (int dn = 0; dn < 4; dn++) {
                    bf16x8 vf = *reinterpret_cast<const bf16x8*>(&VTs[cur][dn*1024 + ll*64 + uv]);
                    o[dn] = __builtin_amdgcn_mfma_f32_16x16x32_bf16(pa, vf, o[dn], 0, 0, 0);
                }
            }
            __builtin_amdgcn_s_setprio(0);
        }
        cur ^= 1;
    }
#undef ASTAGE

    float linv = 1.0f / l_run;
    float i0v = __shfl(linv, lg*4 + 0);
    float i1v = __shfl(linv, lg*4 + 1);
    float i2v = __shfl(linv, lg*4 + 2);
    float i3v = __shfl(linv, lg*4 + 3);
    #pragma unroll
    for (int dn = 0; dn < 4; dn++) {
        og[(size_t)(qw + lg*4 + 0) * QSZ + h*64 + dn*16 + ll] = (__bf16)(o[dn][0] * i0v);
        og[(size_t)(qw + lg*4 + 1) * QSZ + h*64 + dn*16 + ll] = (__bf16)(o[dn][1] * i1v);
        og[(size_t)(qw + lg*4 + 2) * QSZ + h*64 + dn*16 + ll] = (__bf16)(o[dn][2] * i2v);
        og[(size_t)(qw + lg*4 + 3) * QSZ + h*64 + dn*16 + ll] = (__bf16)(o[dn][3] * i3v);
    }
}

// ---------------- launch ----------------
extern "C" void kernel_launch(void* const* d_in, const int* in_sizes, int n_in,
                              void* d_out, int out_size, void* d_ws, size_t ws_size,
                              hipStream_t stream) {
    const int*   positions = (const int*)d_in[0];
    const float* hidden    = (const float*)d_in[1];
    const float* wqkv      = (const float*)d_in[2];
    const float* wo        = (const float*)d_in[3];
    float* out = (float*)d_out;

    char* ws = (char*)d_ws;
    __bf16* hidden_bf = (__bf16*)(ws);                       // 2048x2048
    __bf16* wqkv_t    = (__bf16*)(ws + 8388608);             // 2560x2048
    __bf16* wo_t      = (__bf16*)(ws + 18874368);            // 2048x2048
    __bf16* q_bf      = (__bf16*)(ws + 37748736);            // 2048x2048
    __bf16* k_bf      = (__bf16*)(ws + 46137344);            // 2048x256
    __bf16* vT_bf     = (__bf16*)(ws + 47185920);            // 256x2048 (V^T)
    __bf16* attn_bf   = (__bf16*)(ws + 48234496);            // 2048x2048
    float2* ropetab   = (float2*)(ws + 56623104);            // 2048x32 float2

    prep<<<dim3(6656), dim3(256), 0, stream>>>(
        (const float4*)hidden, (bf16x4*)hidden_bf, wqkv, wo,
        wqkv_t, wo_t, positions, ropetab);

    gemm_qkv<<<dim3(QKVN / 128, T_SEQ / 64), dim3(256), 0, stream>>>(
        hidden_bf, wqkv_t, ropetab, q_bf, k_bf, vT_bf);

    attn_kernel<<<dim3(T_SEQ / 64, 16), dim3(512), 0, stream>>>(
        q_bf, k_bf, vT_bf, attn_bf);

    gemm_out<<<dim3(HIDDEN / 128, T_SEQ / 64), dim3(256), 0, stream>>>(
        attn_bf, wo_t, out, T_SEQ, HIDDEN, QSZ);
}